// Round 3
// baseline (194.029 us; speedup 1.0000x reference)
//
#include <hip/hip_runtime.h>
#include <hip/hip_bf16.h>

// AttentionConv2d: B=8, C_IN=256, H=W=32 (HW=1024), DK=DV=256, NH=8, DKH=DVH=32,
// C_OUT=512, 3x3 conv pad=1. fp32 storage in/out; bf16 intermediates + MFMA.
//
// Workspace (bf16 elements, EXACTLY 16 MB):
//   xT    [8 b][1024 l][256 ci]  @ 0          read by fused conv3+qkv
//   attL  [8 b][1024 l][256 ch]  @ 0          alias of xT (attn writes after fused done)
//   qT    [64 head][1024][32]    @ 2,097,152
//   kR    [64 head][1024][32]    @ 4,194,304
//   vW    [64 head][32][1024]    @ 6,291,456
// prep -> convqkv(fused) -> attn -> attnout.
// R15: attn = R13 (verified passing) with ONE change: K/V LDS staging and both
// in-loop barriers deleted; K/V fragments read directly from global at the
// byte-identical addresses the staging produced. K frag: coalesced bf16x8 at
// kR[head][c*64+t*16+m16][quad*8]. V frag: 2x uint2 at
// vW[head][dt*16+m16][c*64+ks*32+quad*4(+16)]. Waves fully decoupled in the
// K-loop; L1/L2 serve the 16-block/head K/V reuse.

typedef __hip_bfloat16 bf16;
typedef __attribute__((ext_vector_type(8))) short bf16x8;
typedef __attribute__((ext_vector_type(4))) float f32x4;

__device__ __forceinline__ float blo(unsigned int v) { return __uint_as_float(v << 16); }
__device__ __forceinline__ float bhi(unsigned int v) { return __uint_as_float(v & 0xffff0000u); }
__device__ __forceinline__ unsigned short f2bfbits(float f) {
  union { bf16 h; unsigned short u; } cv; cv.h = __float2bfloat16(f); return cv.u;
}
// v_cvt_pk_bf16_f32: dst.lo = bf16(lo), dst.hi = bf16(hi). RNE, 1 VALU op.
__device__ __forceinline__ unsigned int cvt_pk_bf16(float lo, float hi) {
  unsigned int r;
  asm("v_cvt_pk_bf16_f32 %0, %1, %2" : "=v"(r) : "v"(lo), "v"(hi));
  return r;
}
__device__ __forceinline__ float exp2_f(float x) {
#if __has_builtin(__builtin_amdgcn_exp2f)
  return __builtin_amdgcn_exp2f(x);
#else
  return exp2f(x);
#endif
}

// ---------------------------------------------------------------------------
// K0: prep — xT transpose to bf16 + w_out bf16 chunk-blocked into wob0/wob1.
// blocks 0..2047: xT; 2048..2083: w_out. grid 2084.
// ---------------------------------------------------------------------------
__global__ __launch_bounds__(256) void prep_kernel(
    const float* __restrict__ x, const float* __restrict__ wout,
    bf16* __restrict__ xT, bf16* __restrict__ wob0, bf16* __restrict__ wob1)
{
  int bid = blockIdx.x, tid = threadIdx.x;
  if (bid < 2048) {
    __shared__ float t[32 * 33];
    int b = bid >> 8, rem = bid & 255;
    int ci0 = (rem >> 5) * 32, l0 = (rem & 31) * 32;
    {
      int ciL = tid >> 3, lL4 = (tid & 7) * 4;
      float4 v = *(const float4*)(x + (size_t)(b * 256 + ci0 + ciL) * 1024 + l0 + lL4);
      t[ciL * 33 + lL4 + 0] = v.x; t[ciL * 33 + lL4 + 1] = v.y;
      t[ciL * 33 + lL4 + 2] = v.z; t[ciL * 33 + lL4 + 3] = v.w;
    }
    __syncthreads();
    {
      int lL = tid >> 3, cS = (tid & 7) * 4;
      unsigned int p0 = (unsigned int)f2bfbits(t[(cS + 0) * 33 + lL]) |
                        ((unsigned int)f2bfbits(t[(cS + 1) * 33 + lL]) << 16);
      unsigned int p1 = (unsigned int)f2bfbits(t[(cS + 2) * 33 + lL]) |
                        ((unsigned int)f2bfbits(t[(cS + 3) * 33 + lL]) << 16);
      uint2 u2; u2.x = p0; u2.y = p1;
      *(uint2*)(xT + ((size_t)(b * 1024) + l0 + lL) * 256 + ci0 + cS) = u2;
    }
  } else {
    int t0 = (bid - 2048) * 256 + tid;       // 0..9215
#pragma unroll
    for (int s = 0; s < 8; ++s) {
      int u = s * 9216 + t0;                 // dst uint4 index 0..73727
      int chunkblk = u / 2304;
      int within = u - chunkblk * 2304;
      int co63 = within / 36;
      int r = within - co63 * 36;            // kidx*4 + cig
      int kidx = r >> 2, cig = r & 3;
      int co = (chunkblk >> 3) * 64 + co63;
      int ci = (chunkblk & 7) * 32 + cig * 8;
      union { unsigned short h[8]; uint4 u4; } pk;
#pragma unroll
      for (int j = 0; j < 8; ++j)
        pk.h[j] = f2bfbits(wout[(size_t)(co * 256 + ci + j) * 9 + kidx]);
      bf16* dst = (chunkblk < 28) ? (wob0 + (size_t)chunkblk * 18432)
                                  : (wob1 + (size_t)(chunkblk - 28) * 18432);
      *(uint4*)(dst + (size_t)within * 8) = pk.u4;
    }
  }
}

// ---------------------------------------------------------------------------
// K1 (fused): blocks 0..255 = conv3 (3x3, MFMA shift-GEMM, prepacked weights);
// 256..1023 = qkv GEMM. Both only read xT -> co-resident, mutual latency hiding.
// ---------------------------------------------------------------------------
__global__ __launch_bounds__(256) void convqkv_kernel(
    const bf16* __restrict__ xT,
    const bf16* __restrict__ wob0, const bf16* __restrict__ wob1,
    const float* __restrict__ b_out, float* __restrict__ out,
    const float* __restrict__ wq, const float* __restrict__ b_qkv,
    bf16* __restrict__ qT, bf16* __restrict__ kR, bf16* __restrict__ vW)
{
  __shared__ __align__(16) short smem[27104];
  int tid = threadIdx.x, lane = tid & 63, wave = tid >> 6;
  int m16 = lane & 15, quad = lane >> 4;

  if (blockIdx.x < 256) {
    short* wS = smem;            // [64 co][296]
    short* xS = smem + 18944;    // [6 rows][34 cols][40]
    int bid = blockIdx.x;
    int rc = bid & 7, cotile = (bid >> 3) & 3, b = bid >> 5;
    int y0 = rc * 4;

    f32x4 acc[8];
#pragma unroll
    for (int t = 0; t < 8; ++t) acc[t] = (f32x4){0.f, 0.f, 0.f, 0.f};

    for (int ck = 0; ck < 8; ++ck) {
      __syncthreads();
      int cb = cotile * 8 + ck;
      const bf16* wbase = (cb < 28) ? (wob0 + (size_t)cb * 18432)
                                    : (wob1 + (size_t)(cb - 28) * 18432);
#pragma unroll
      for (int r = 0; r < 9; ++r) {
        int u = r * 256 + tid;
        *(uint4*)(wS + (u / 36) * 296 + (u % 36) * 8) = *(const uint4*)(wbase + (size_t)u * 8);
      }
#pragma unroll
      for (int r = 0; r < 3; ++r) {
        int u = r * 256 + tid;
        int pos = u >> 2, seg = u & 3;
        int row = pos >> 5, col = pos & 31;
        int gy = y0 - 1 + row;
        uint4 val = make_uint4(0u, 0u, 0u, 0u);
        if (gy >= 0 && gy < 32)
          val = *(const uint4*)(xT + ((size_t)(b * 1024) + gy * 32 + col) * 256 + ck * 32 + seg * 8);
        *(uint4*)(xS + (row * 34 + col + 1) * 40 + seg * 8) = val;
      }
      if (tid < 48) {
        int pos = tid >> 2, seg = tid & 3;
        int row = pos >> 1, side = pos & 1;
        *(uint4*)(xS + (row * 34 + side * 33) * 40 + seg * 8) = make_uint4(0u, 0u, 0u, 0u);
      }
      __syncthreads();
#pragma unroll
      for (int kidx = 0; kidx < 9; ++kidx) {
        int dy = kidx / 3, dx = kidx - dy * 3;
        bf16x8 af = *(const bf16x8*)(wS + (wave * 16 + m16) * 296 + kidx * 32 + quad * 8);
#pragma unroll
        for (int t = 0; t < 8; ++t) {
          int row = (t >> 1) + dy;
          int col = (t & 1) * 16 + m16 + dx;
          bf16x8 bf = *(const bf16x8*)(xS + (row * 34 + col) * 40 + quad * 8);
          acc[t] = __builtin_amdgcn_mfma_f32_16x16x32_bf16(af, bf, acc[t], 0, 0, 0);
        }
      }
    }

    int cob = cotile * 64 + wave * 16 + quad * 4;
#pragma unroll
    for (int i = 0; i < 4; ++i) {
      float bv = b_out[cob + i];
#pragma unroll
      for (int t = 0; t < 8; ++t) {
        int y = y0 + (t >> 1), xc = (t & 1) * 16 + m16;
        out[((size_t)(b * 512) + cob + i) * 1024 + y * 32 + xc] = acc[t][i] + bv;
      }
    }
  } else {
    short* aS = smem;            // [64][72]
    short* bS = smem + 4608;     // [128][72]
    int bid2 = blockIdx.x - 256;
    int ltile = bid2 & 7;
    int rest = bid2 >> 3;
    int ctile = rest % 12;
    int b = rest / 12;
    int l0 = ltile * 128;
    int cbase = ctile * 64;

    f32x4 acc[8];
#pragma unroll
    for (int t = 0; t < 8; ++t) acc[t] = (f32x4){0.f, 0.f, 0.f, 0.f};

    for (int ck = 0; ck < 4; ++ck) {
      __syncthreads();
#pragma unroll
      for (int r = 0; r < 4; ++r) {
        int u = r * 256 + tid;
        int c = u >> 4, s4 = u & 15;
        float4 v = *(const float4*)(wq + (size_t)(cbase + c) * 256 + ck * 64 + s4 * 4);
        unsigned int p0 = (unsigned int)f2bfbits(v.x) | ((unsigned int)f2bfbits(v.y) << 16);
        unsigned int p1 = (unsigned int)f2bfbits(v.z) | ((unsigned int)f2bfbits(v.w) << 16);
        uint2 u2; u2.x = p0; u2.y = p1;
        *(uint2*)(aS + c * 72 + s4 * 4) = u2;
      }
#pragma unroll
      for (int r = 0; r < 4; ++r) {
        int u = r * 256 + tid;
        int l = u >> 3, seg = u & 7;
        *(uint4*)(bS + l * 72 + seg * 8) =
            *(const uint4*)(xT + ((size_t)(b * 1024) + l0 + l) * 256 + ck * 64 + seg * 8);
      }
      __syncthreads();
#pragma unroll
      for (int ks = 0; ks < 2; ++ks) {
        bf16x8 af = *(const bf16x8*)(aS + (wave * 16 + m16) * 72 + ks * 32 + quad * 8);
#pragma unroll
        for (int t = 0; t < 8; ++t) {
          bf16x8 bf = *(const bf16x8*)(bS + (t * 16 + m16) * 72 + ks * 32 + quad * 8);
          acc[t] = __builtin_amdgcn_mfma_f32_16x16x32_bf16(af, bf, acc[t], 0, 0, 0);
        }
      }
    }

    __syncthreads();
    short* ldsT = smem + wave * 3072;
    int cb = cbase + wave * 16;
    bool isq = (ctile < 4);
    float bv[4];
#pragma unroll
    for (int i = 0; i < 4; ++i) bv[i] = b_qkv[cb + quad * 4 + i];
#pragma unroll
    for (int t = 0; t < 8; ++t) {
#pragma unroll
      for (int i = 0; i < 4; ++i) {
        float v = acc[t][i] + bv[i];
        if (isq) v *= 0.17677669529663689f;  // 32^-0.5, pre-rel-logits
        ldsT[(t * 16 + m16) * 24 + quad * 4 + i] = (short)f2bfbits(v);
      }
    }
    if (ctile < 8) {
      bf16* dst = isq ? qT : kR;
      int coff = isq ? cb : cb - 256;
#pragma unroll
      for (int rep = 0; rep < 4; ++rep) {
        int u = rep * 64 + lane;
        int l = u >> 1, half = u & 1;
        int c0 = coff + half * 8;
        int head = b * 8 + (c0 >> 5), d0 = c0 & 31;
        *(uint4*)(dst + ((size_t)head * 1024 + l0 + l) * 32 + d0) =
            *(const uint4*)(ldsT + l * 24 + half * 8);
      }
    } else {
      int dcol = lane >> 2, lg = lane & 3;
      int c2 = (cb - 512) + dcol;
      int head = b * 8 + (c2 >> 5), gd = c2 & 31;
#pragma unroll
      for (int s = 0; s < 4; ++s) {
        union { unsigned int w[4]; uint4 u4; } pk;
#pragma unroll
        for (int p = 0; p < 4; ++p) {
          int j0 = lg * 32 + s * 8 + p * 2;
          unsigned int u0 = (unsigned short)ldsT[j0 * 24 + dcol];
          unsigned int u1 = (unsigned short)ldsT[(j0 + 1) * 24 + dcol];
          pk.w[p] = u0 | (u1 << 16);
        }
        *(uint4*)(vW + ((size_t)head * 32 + gd) * 1024 + l0 + lg * 32 + s * 8) = pk.u4;
      }
    }
  }
}

// ---------------------------------------------------------------------------
// K3: MFMA attention, R15 = R13 structure (grid 1024, 64 q/block) with direct
// global K/V fragment reads, NO in-loop barriers, no K/V LDS staging.
// QK^T swapped: sacc[t] = mfma(Kfrag, Qfrag) -> lane holds S^T[key][q=m16].
// P = exp2(fma(S,L2E,rw+rh)) packed via cvt_pk stays in registers; the 8
// dwords ARE the PV B-fragment under kappa(quad,j)=(j>>2)*16+quad*4+(j&3),
// matched on the V side by two uint2 global reads (quad*4 and quad*4+16).
// LDS map (27648 B): stgF f32 [63][36] @0 (9072, prologue scratch);
//   rhS f32 [32 j][68 r] @9728; rwS f32 [64 r][36 j] @18432.
// rw/rh tables pre-scaled by log2e.
// ---------------------------------------------------------------------------
__global__ __launch_bounds__(256) void attn_mfma_kernel(
    const bf16* __restrict__ qT, const bf16* __restrict__ kR, const bf16* __restrict__ vW,
    const float* __restrict__ krw, const float* __restrict__ krh,
    bf16* __restrict__ attL)
{
  __shared__ __align__(16) char smem[27648];
  float* stgF = (float*)smem;
  float* rhS  = (float*)(smem + 9728);
  float* rwS  = (float*)(smem + 18432);

  const float L2E = 1.4426950408889634f;

  int tid = threadIdx.x;
  int lane = tid & 63, wave = tid >> 6;
  int m16 = lane & 15, quad = lane >> 4;
  int bid = blockIdx.x;
  // same head -> same blockIdx mod 8 -> same XCD (round-robin heuristic)
  int head = ((bid & 7) << 3) | ((bid >> 3) & 7);
  int qt = bid >> 6;                 // 0..15, 64 q rows per block
  int row0 = qt * 64;
  int b = head >> 3, h = head & 7;

  // per-thread prologue identity: row r (0..63), j-segment (0..3)
  int r = tid >> 2, jseg = tid & 3;
  float q32[32];
  {
    const bf16* qp = qT + ((size_t)head * 1024 + row0 + r) * 32;
#pragma unroll
    for (int s4 = 0; s4 < 4; ++s4) {
      uint4 u = ((const uint4*)qp)[s4];
      q32[s4 * 8 + 0] = blo(u.x); q32[s4 * 8 + 1] = bhi(u.x);
      q32[s4 * 8 + 2] = blo(u.y); q32[s4 * 8 + 3] = bhi(u.y);
      q32[s4 * 8 + 4] = blo(u.z); q32[s4 * 8 + 5] = bhi(u.z);
      q32[s4 * 8 + 6] = blo(u.w); q32[s4 * 8 + 7] = bhi(u.w);
    }
  }

  // ---- P0: stage krw f32 (stride 36) ----
  for (int i = tid; i < 504; i += 256) {
    int row = i >> 3, d0 = (i & 7) * 4;
    *(float4*)(stgF + row * 36 + d0) = *(const float4*)(krw + row * 32 + d0);
  }
  __syncthreads();

  // ---- P1: rwS[r][j] = log2e * (q[r] . krw[j - (r&31) + 31]) ----
  {
    int qi = r & 31;
#pragma unroll
    for (int jj2 = 0; jj2 < 2; ++jj2) {
      float rv[4];
#pragma unroll
      for (int jp = 0; jp < 4; ++jp) {
        int j = jseg * 8 + jj2 * 4 + jp;
        const float* kw = stgF + (j - qi + 31) * 36;
        float s1 = 0.f;
#pragma unroll
        for (int d4 = 0; d4 < 8; ++d4) {
          float4 kv = *(const float4*)(kw + d4 * 4);
          s1 += q32[d4 * 4 + 0] * kv.x + q32[d4 * 4 + 1] * kv.y +
                q32[d4 * 4 + 2] * kv.z + q32[d4 * 4 + 3] * kv.w;
        }
        rv[jp] = s1 * L2E;
      }
      *(float4*)(rwS + r * 36 + jseg * 8 + jj2 * 4) = make_float4(rv[0], rv[1], rv[2], rv[3]);
    }
  }
  __syncthreads();

  // ---- P2: stage krh over stgF ----
  for (int i = tid; i < 504; i += 256) {
    int row = i >> 3, d0 = (i & 7) * 4;
    *(float4*)(stgF + row * 36 + d0) = *(const float4*)(krh + row * 32 + d0);
  }
  __syncthreads();

  // ---- P3: rhS[j][r] = log2e * (q[r] . krh[j - qy + 31]) ----
  {
    int qy = qt * 2 + (r >> 5);
#pragma unroll
    for (int jj = 0; jj < 8; ++jj) {
      int j = jseg * 8 + jj;
      const float* kh = stgF + (j - qy + 31) * 36;
      float s2 = 0.f;
#pragma unroll
      for (int d4 = 0; d4 < 8; ++d4) {
        float4 kv = *(const float4*)(kh + d4 * 4);
        s2 += q32[d4 * 4 + 0] * kv.x + q32[d4 * 4 + 1] * kv.y +
              q32[d4 * 4 + 2] * kv.z + q32[d4 * 4 + 3] * kv.w;
      }
      rhS[j * 68 + r] = s2 * L2E;
    }
  }
  __syncthreads();   // rhS/rwS read-only from here; NO more barriers

  // ---- P4: Q fragment (B-operand) + chunk-invariant RW registers (row=q=m16)
  bf16x8 afrag = *(const bf16x8*)(
      qT + ((size_t)head * 1024 + row0 + wave * 16 + m16) * 32 + quad * 8);
  float rwreg[2][4];
  {
    float4 rw0 = *(const float4*)(rwS + (wave * 16 + m16) * 36 + quad * 4);
    float4 rw1 = *(const float4*)(rwS + (wave * 16 + m16) * 36 + 16 + quad * 4);
    rwreg[0][0] = rw0.x; rwreg[0][1] = rw0.y; rwreg[0][2] = rw0.z; rwreg[0][3] = rw0.w;
    rwreg[1][0] = rw1.x; rwreg[1][1] = rw1.y; rwreg[1][2] = rw1.z; rwreg[1][3] = rw1.w;
  }

  // per-lane global fragment pointers (byte-identical to what staging produced)
  const bf16* kp = kR + (size_t)head * 32768 + m16 * 32 + quad * 8;     // +c*2048 +t*512
  const bf16* vp = vW + (size_t)head * 32768 + m16 * 1024 + quad * 4;   // +dt*16384 +c*64 +ks*32(+16)

  f32x4 oacc[2];
  oacc[0] = (f32x4){0.f, 0.f, 0.f, 0.f};
  oacc[1] = (f32x4){0.f, 0.f, 0.f, 0.f};
  float rsp = 0.f;

  for (int c = 0; c < 16; ++c) {
    // RH for this chunk (read-only LDS broadcast; key_y = c*2 + (t>>1))
    float rh0 = rhS[(c * 2 + 0) * 68 + wave * 16 + m16];
    float rh1 = rhS[(c * 2 + 1) * 68 + wave * 16 + m16];

    // QK^T swapped: A = K frag (rows=keys), B = Qfrag (cols=q)
    f32x4 sacc[4];
#pragma unroll
    for (int t = 0; t < 4; ++t) {
      bf16x8 kf = *(const bf16x8*)(kp + c * 2048 + t * 512);
      f32x4 z = (f32x4){0.f, 0.f, 0.f, 0.f};
      sacc[t] = __builtin_amdgcn_mfma_f32_16x16x32_bf16(kf, afrag, z, 0, 0, 0);
    }

    // softmax numerators in-register (lane q = m16, key = t*16+quad*4+i)
    unsigned int pk[4][2];
#pragma unroll
    for (int t = 0; t < 4; ++t) {
      float rh = (t < 2) ? rh0 : rh1;
      float e0 = exp2_f(fmaf(sacc[t][0], L2E, rwreg[t & 1][0] + rh));
      float e1 = exp2_f(fmaf(sacc[t][1], L2E, rwreg[t & 1][1] + rh));
      float e2 = exp2_f(fmaf(sacc[t][2], L2E, rwreg[t & 1][2] + rh));
      float e3 = exp2_f(fmaf(sacc[t][3], L2E, rwreg[t & 1][3] + rh));
      rsp += (e0 + e1) + (e2 + e3);
      pk[t][0] = cvt_pk_bf16(e0, e1);
      pk[t][1] = cvt_pk_bf16(e2, e3);
    }

    // PV: O^T = mfma(Vfrag, P^T). kappa = ks*32 + (j>>2)*16 + quad*4 + (j&3).
#pragma unroll
    for (int ks = 0; ks < 2; ++ks) {
      union { unsigned int w[4]; bf16x8 v; } pf;
      pf.w[0] = pk[2 * ks][0];     pf.w[1] = pk[2 * ks][1];
      pf.w[2] = pk[2 * ks + 1][0]; pf.w[3] = pk[2 * ks + 1][1];
#pragma unroll
      for (int dt = 0; dt < 2; ++dt) {
        const bf16* vb = vp + dt * 16384 + c * 64 + ks * 32;
        union { uint2 u[2]; bf16x8 v; } vf;
        vf.u[0] = *(const uint2*)(vb);
        vf.u[1] = *(const uint2*)(vb + 16);
        oacc[dt] = __builtin_amdgcn_mfma_f32_16x16x32_bf16(vf.v, pf.v, oacc[dt], 0, 0, 0);
      }
    }
  }

  // ---- epilogue: reduce row-sums across quads, normalize, store ----
  rsp += __shfl_xor(rsp, 16, 64);
  rsp += __shfl_xor(rsp, 32, 64);
  float invs = 1.0f / rsp;
  int grow = row0 + wave * 16 + m16;
#pragma unroll
  for (int dt = 0; dt < 2; ++dt) {
    uint2 st;
    st.x = cvt_pk_bf16(oacc[dt][0] * invs, oacc[dt][1] * invs);
    st.y = cvt_pk_bf16(oacc[dt][2] * invs, oacc[dt][3] * invs);
    *(uint2*)(attL + ((size_t)b * 1024 + grow) * 256 + h * 32 + dt * 16 + quad * 4) = st;
  }
}

// ---------------------------------------------------------------------------
// K4: attnout 1x1 conv as MFMA GEMM 256 x 1024 x 256 per batch. (R6 version)
// Runs last; overwrites the d_out ch256+ regions that hosted wo_bf.
// ---------------------------------------------------------------------------
__global__ __launch_bounds__(256) void attnout_mfma_kernel(
    const bf16* __restrict__ attL, const float* __restrict__ w, const float* __restrict__ bias,
    float* __restrict__ out)
{
  __shared__ __align__(16) short smem[13824];
  short* aS = smem;            // [64 co][72]
  short* bS = smem + 4608;     // [128 l][72]

  int tid = threadIdx.x, lane = tid & 63, wave = tid >> 6;
  int m16 = lane & 15, quad = lane >> 4;
  int l0 = blockIdx.x * 128;
  int cotile = blockIdx.y;
  int b = blockIdx.z;
  int cbase = cotile * 64;

  f32x4 acc[8];
#pragma unroll
  for (int t = 0; t < 8; ++t) acc[t] = (f32x4){0.f, 0.f, 0.f, 0.f};

  for (int ck = 0; ck < 4; ++ck) {
    __syncthreads();
#pragma unroll
    for (int r = 0; r < 4; ++r) {
      int u = r * 256 + tid;
      int c = u >> 4, s4 = u & 15;
      float4 v = *(const float4*)(w + (size_t)(cbase + c) * 256 + ck * 64 + s4 * 4);
      unsigned int p0 = (unsigned int)f2bfbits(v.x) | ((unsigned int)f2bfbits(v.y) << 16);
      unsigned int p1 = (unsigned int)f2bfbits(v.z) | ((unsigned int)f2bfbits(v.w) << 16);
      uint2 u2; u2.x = p0; u2.y = p1;
      *(uint2*)(aS + c * 72 + s4 * 4) = u2;
    }
#pragma unroll
    for (int r = 0; r < 4; ++r) {
      int u = r * 256 + tid;
      int l = u >> 3, seg = u & 7;
      *(uint4*)(bS + l * 72 + seg * 8) =
          *(const uint4*)(attL + ((size_t)(b * 1024) + l0 + l) * 256 + ck * 64 + seg * 8);
    }
    __syncthreads();
#pragma unroll
    for (int ks = 0; ks < 2; ++ks) {
      bf16x8 af = *(const bf16x8*)(aS + (wave * 16 + m16) * 72 + ks * 32 + quad * 8);
#pragma unroll
      for (int t = 0; t < 8; ++t) {
        bf16x8 bf = *(const bf16x8*)(bS + (t * 16 + m16) * 72 + ks * 32 + quad * 8);
        acc[t] = __builtin_amdgcn_mfma_f32_16x16x32_bf16(af, bf, acc[t], 0, 0, 0);
      }
    }
  }

  int co = cbase + wave * 16 + quad * 4;
#pragma unroll
  for (int i = 0; i < 4; ++i) {
    float bv = bias[co + i];
    size_t obase = ((size_t)(b * 512) + 256 + co + i) * 1024 + l0;
#pragma unroll
    for (int t = 0; t < 8; ++t)
      out[obase + t * 16 + m16] = acc[t][i] + bv;
  }
}

// ---------------------------------------------------------------------------
extern "C" void kernel_launch(void* const* d_in, const int* in_sizes, int n_in,
                              void* d_out, int out_size, void* d_ws, size_t ws_size,
                              hipStream_t stream) {
  const float* x      = (const float*)d_in[0];
  const float* w_qkv  = (const float*)d_in[1];
  const float* b_qkv  = (const float*)d_in[2];
  const float* w_attn = (const float*)d_in[3];
  const float* b_attn = (const float*)d_in[4];
  const float* w_out  = (const float*)d_in[5];
  const float* b_out  = (const float*)d_in[6];
  const float* krw    = (const float*)d_in[7];
  const float* krh    = (const float*)d_in[8];
  float* out = (float*)d_out;

  bf16* ws    = (bf16*)d_ws;
  bf16* xT    = ws;                 // [0, 2,097,152)  read by fused conv3+qkv
  bf16* attL  = ws;                 // alias of xT     (attn -> attnout, after fused)
  bf16* qT    = ws + 2097152;       // [2,097,152, 4,194,304)
  bf16* kR    = ws + 4194304;       // [4,194,304, 6,291,456)
  bf16* vW    = ws + 6291456;       // [6,291,456, 8,388,608)  exact 16 MB fit

  // wo_bf in d_out's attention half (dead until attnout overwrites it)
  bf16* wob0 = (bf16*)(out + (size_t)(0 * 512 + 256) * 1024);
  bf16* wob1 = (bf16*)(out + (size_t)(1 * 512 + 256) * 1024);

  prep_kernel<<<dim3(2084), 256, 0, stream>>>(x, w_out, xT, wob0, wob1);
  convqkv_kernel<<<dim3(1024), 256, 0, stream>>>(xT, wob0, wob1, b_out, out,
                                                 w_qkv, b_qkv, qT, kR, vW);
  attn_mfma_kernel<<<dim3(1024), 256, 0, stream>>>(qT, kR, vW, krw, krh, attL);
  attnout_mfma_kernel<<<dim3(8, 4, 8), 256, 0, stream>>>(attL, w_attn, b_attn, out);
}

// Round 4
// 164.768 us; speedup vs baseline: 1.1776x; 1.1776x over previous
//
#include <hip/hip_runtime.h>
#include <hip/hip_bf16.h>

// AttentionConv2d: B=8, C_IN=256, H=W=32 (HW=1024), DK=DV=256, NH=8, DKH=DVH=32,
// C_OUT=512, 3x3 conv pad=1. fp32 storage in/out; bf16 intermediates + MFMA.
//
// Workspace (bf16 elements, EXACTLY 16 MB):
//   xT    [8 b][1024 l][256 ci]  @ 0          read by fused conv3+qkv
//   attL  [8 b][1024 l][256 ch]  @ 0          alias of xT (attn writes after fused done)
//   qT    [64 head][1024][32]    @ 2,097,152
//   kR    [64 head][1024][32]    @ 4,194,304
//   vW    [64 head][32][1024]    @ 6,291,456
// prep -> convqkv(fused) -> attn -> attnout.
// R16: attn hybrid. K fragments read DIRECTLY from global (coalesced bf16x8 at
// kR[head][c*64+t*16+m16][quad*8] — address math proven in R15), register
// double-buffered (kfr[2][4], prefetch c+1 during c). V stays LDS-staged
// (R13-identical indexing) but DOUBLE-BUFFERED -> exactly one barrier per
// chunk. kS deleted. Prologue/epilogue identical to R13 (verified passing).

typedef __hip_bfloat16 bf16;
typedef __attribute__((ext_vector_type(8))) short bf16x8;
typedef __attribute__((ext_vector_type(4))) float f32x4;

__device__ __forceinline__ float blo(unsigned int v) { return __uint_as_float(v << 16); }
__device__ __forceinline__ float bhi(unsigned int v) { return __uint_as_float(v & 0xffff0000u); }
__device__ __forceinline__ unsigned short f2bfbits(float f) {
  union { bf16 h; unsigned short u; } cv; cv.h = __float2bfloat16(f); return cv.u;
}
// v_cvt_pk_bf16_f32: dst.lo = bf16(lo), dst.hi = bf16(hi). RNE, 1 VALU op.
__device__ __forceinline__ unsigned int cvt_pk_bf16(float lo, float hi) {
  unsigned int r;
  asm("v_cvt_pk_bf16_f32 %0, %1, %2" : "=v"(r) : "v"(lo), "v"(hi));
  return r;
}
__device__ __forceinline__ float exp2_f(float x) {
#if __has_builtin(__builtin_amdgcn_exp2f)
  return __builtin_amdgcn_exp2f(x);
#else
  return exp2f(x);
#endif
}

// ---------------------------------------------------------------------------
// K0: prep — xT transpose to bf16 + w_out bf16 chunk-blocked into wob0/wob1.
// blocks 0..2047: xT; 2048..2083: w_out. grid 2084.
// ---------------------------------------------------------------------------
__global__ __launch_bounds__(256) void prep_kernel(
    const float* __restrict__ x, const float* __restrict__ wout,
    bf16* __restrict__ xT, bf16* __restrict__ wob0, bf16* __restrict__ wob1)
{
  int bid = blockIdx.x, tid = threadIdx.x;
  if (bid < 2048) {
    __shared__ float t[32 * 33];
    int b = bid >> 8, rem = bid & 255;
    int ci0 = (rem >> 5) * 32, l0 = (rem & 31) * 32;
    {
      int ciL = tid >> 3, lL4 = (tid & 7) * 4;
      float4 v = *(const float4*)(x + (size_t)(b * 256 + ci0 + ciL) * 1024 + l0 + lL4);
      t[ciL * 33 + lL4 + 0] = v.x; t[ciL * 33 + lL4 + 1] = v.y;
      t[ciL * 33 + lL4 + 2] = v.z; t[ciL * 33 + lL4 + 3] = v.w;
    }
    __syncthreads();
    {
      int lL = tid >> 3, cS = (tid & 7) * 4;
      unsigned int p0 = (unsigned int)f2bfbits(t[(cS + 0) * 33 + lL]) |
                        ((unsigned int)f2bfbits(t[(cS + 1) * 33 + lL]) << 16);
      unsigned int p1 = (unsigned int)f2bfbits(t[(cS + 2) * 33 + lL]) |
                        ((unsigned int)f2bfbits(t[(cS + 3) * 33 + lL]) << 16);
      uint2 u2; u2.x = p0; u2.y = p1;
      *(uint2*)(xT + ((size_t)(b * 1024) + l0 + lL) * 256 + ci0 + cS) = u2;
    }
  } else {
    int t0 = (bid - 2048) * 256 + tid;       // 0..9215
#pragma unroll
    for (int s = 0; s < 8; ++s) {
      int u = s * 9216 + t0;                 // dst uint4 index 0..73727
      int chunkblk = u / 2304;
      int within = u - chunkblk * 2304;
      int co63 = within / 36;
      int r = within - co63 * 36;            // kidx*4 + cig
      int kidx = r >> 2, cig = r & 3;
      int co = (chunkblk >> 3) * 64 + co63;
      int ci = (chunkblk & 7) * 32 + cig * 8;
      union { unsigned short h[8]; uint4 u4; } pk;
#pragma unroll
      for (int j = 0; j < 8; ++j)
        pk.h[j] = f2bfbits(wout[(size_t)(co * 256 + ci + j) * 9 + kidx]);
      bf16* dst = (chunkblk < 28) ? (wob0 + (size_t)chunkblk * 18432)
                                  : (wob1 + (size_t)(chunkblk - 28) * 18432);
      *(uint4*)(dst + (size_t)within * 8) = pk.u4;
    }
  }
}

// ---------------------------------------------------------------------------
// K1 (fused): blocks 0..255 = conv3 (3x3, MFMA shift-GEMM, prepacked weights);
// 256..1023 = qkv GEMM. Both only read xT -> co-resident, mutual latency hiding.
// ---------------------------------------------------------------------------
__global__ __launch_bounds__(256) void convqkv_kernel(
    const bf16* __restrict__ xT,
    const bf16* __restrict__ wob0, const bf16* __restrict__ wob1,
    const float* __restrict__ b_out, float* __restrict__ out,
    const float* __restrict__ wq, const float* __restrict__ b_qkv,
    bf16* __restrict__ qT, bf16* __restrict__ kR, bf16* __restrict__ vW)
{
  __shared__ __align__(16) short smem[27104];
  int tid = threadIdx.x, lane = tid & 63, wave = tid >> 6;
  int m16 = lane & 15, quad = lane >> 4;

  if (blockIdx.x < 256) {
    short* wS = smem;            // [64 co][296]
    short* xS = smem + 18944;    // [6 rows][34 cols][40]
    int bid = blockIdx.x;
    int rc = bid & 7, cotile = (bid >> 3) & 3, b = bid >> 5;
    int y0 = rc * 4;

    f32x4 acc[8];
#pragma unroll
    for (int t = 0; t < 8; ++t) acc[t] = (f32x4){0.f, 0.f, 0.f, 0.f};

    for (int ck = 0; ck < 8; ++ck) {
      __syncthreads();
      int cb = cotile * 8 + ck;
      const bf16* wbase = (cb < 28) ? (wob0 + (size_t)cb * 18432)
                                    : (wob1 + (size_t)(cb - 28) * 18432);
#pragma unroll
      for (int r = 0; r < 9; ++r) {
        int u = r * 256 + tid;
        *(uint4*)(wS + (u / 36) * 296 + (u % 36) * 8) = *(const uint4*)(wbase + (size_t)u * 8);
      }
#pragma unroll
      for (int r = 0; r < 3; ++r) {
        int u = r * 256 + tid;
        int pos = u >> 2, seg = u & 3;
        int row = pos >> 5, col = pos & 31;
        int gy = y0 - 1 + row;
        uint4 val = make_uint4(0u, 0u, 0u, 0u);
        if (gy >= 0 && gy < 32)
          val = *(const uint4*)(xT + ((size_t)(b * 1024) + gy * 32 + col) * 256 + ck * 32 + seg * 8);
        *(uint4*)(xS + (row * 34 + col + 1) * 40 + seg * 8) = val;
      }
      if (tid < 48) {
        int pos = tid >> 2, seg = tid & 3;
        int row = pos >> 1, side = pos & 1;
        *(uint4*)(xS + (row * 34 + side * 33) * 40 + seg * 8) = make_uint4(0u, 0u, 0u, 0u);
      }
      __syncthreads();
#pragma unroll
      for (int kidx = 0; kidx < 9; ++kidx) {
        int dy = kidx / 3, dx = kidx - dy * 3;
        bf16x8 af = *(const bf16x8*)(wS + (wave * 16 + m16) * 296 + kidx * 32 + quad * 8);
#pragma unroll
        for (int t = 0; t < 8; ++t) {
          int row = (t >> 1) + dy;
          int col = (t & 1) * 16 + m16 + dx;
          bf16x8 bf = *(const bf16x8*)(xS + (row * 34 + col) * 40 + quad * 8);
          acc[t] = __builtin_amdgcn_mfma_f32_16x16x32_bf16(af, bf, acc[t], 0, 0, 0);
        }
      }
    }

    int cob = cotile * 64 + wave * 16 + quad * 4;
#pragma unroll
    for (int i = 0; i < 4; ++i) {
      float bv = b_out[cob + i];
#pragma unroll
      for (int t = 0; t < 8; ++t) {
        int y = y0 + (t >> 1), xc = (t & 1) * 16 + m16;
        out[((size_t)(b * 512) + cob + i) * 1024 + y * 32 + xc] = acc[t][i] + bv;
      }
    }
  } else {
    short* aS = smem;            // [64][72]
    short* bS = smem + 4608;     // [128][72]
    int bid2 = blockIdx.x - 256;
    int ltile = bid2 & 7;
    int rest = bid2 >> 3;
    int ctile = rest % 12;
    int b = rest / 12;
    int l0 = ltile * 128;
    int cbase = ctile * 64;

    f32x4 acc[8];
#pragma unroll
    for (int t = 0; t < 8; ++t) acc[t] = (f32x4){0.f, 0.f, 0.f, 0.f};

    for (int ck = 0; ck < 4; ++ck) {
      __syncthreads();
#pragma unroll
      for (int r = 0; r < 4; ++r) {
        int u = r * 256 + tid;
        int c = u >> 4, s4 = u & 15;
        float4 v = *(const float4*)(wq + (size_t)(cbase + c) * 256 + ck * 64 + s4 * 4);
        unsigned int p0 = (unsigned int)f2bfbits(v.x) | ((unsigned int)f2bfbits(v.y) << 16);
        unsigned int p1 = (unsigned int)f2bfbits(v.z) | ((unsigned int)f2bfbits(v.w) << 16);
        uint2 u2; u2.x = p0; u2.y = p1;
        *(uint2*)(aS + c * 72 + s4 * 4) = u2;
      }
#pragma unroll
      for (int r = 0; r < 4; ++r) {
        int u = r * 256 + tid;
        int l = u >> 3, seg = u & 7;
        *(uint4*)(bS + l * 72 + seg * 8) =
            *(const uint4*)(xT + ((size_t)(b * 1024) + l0 + l) * 256 + ck * 64 + seg * 8);
      }
      __syncthreads();
#pragma unroll
      for (int ks = 0; ks < 2; ++ks) {
        bf16x8 af = *(const bf16x8*)(aS + (wave * 16 + m16) * 72 + ks * 32 + quad * 8);
#pragma unroll
        for (int t = 0; t < 8; ++t) {
          bf16x8 bf = *(const bf16x8*)(bS + (t * 16 + m16) * 72 + ks * 32 + quad * 8);
          acc[t] = __builtin_amdgcn_mfma_f32_16x16x32_bf16(af, bf, acc[t], 0, 0, 0);
        }
      }
    }

    __syncthreads();
    short* ldsT = smem + wave * 3072;
    int cb = cbase + wave * 16;
    bool isq = (ctile < 4);
    float bv[4];
#pragma unroll
    for (int i = 0; i < 4; ++i) bv[i] = b_qkv[cb + quad * 4 + i];
#pragma unroll
    for (int t = 0; t < 8; ++t) {
#pragma unroll
      for (int i = 0; i < 4; ++i) {
        float v = acc[t][i] + bv[i];
        if (isq) v *= 0.17677669529663689f;  // 32^-0.5, pre-rel-logits
        ldsT[(t * 16 + m16) * 24 + quad * 4 + i] = (short)f2bfbits(v);
      }
    }
    if (ctile < 8) {
      bf16* dst = isq ? qT : kR;
      int coff = isq ? cb : cb - 256;
#pragma unroll
      for (int rep = 0; rep < 4; ++rep) {
        int u = rep * 64 + lane;
        int l = u >> 1, half = u & 1;
        int c0 = coff + half * 8;
        int head = b * 8 + (c0 >> 5), d0 = c0 & 31;
        *(uint4*)(dst + ((size_t)head * 1024 + l0 + l) * 32 + d0) =
            *(const uint4*)(ldsT + l * 24 + half * 8);
      }
    } else {
      int dcol = lane >> 2, lg = lane & 3;
      int c2 = (cb - 512) + dcol;
      int head = b * 8 + (c2 >> 5), gd = c2 & 31;
#pragma unroll
      for (int s = 0; s < 4; ++s) {
        union { unsigned int w[4]; uint4 u4; } pk;
#pragma unroll
        for (int p = 0; p < 4; ++p) {
          int j0 = lg * 32 + s * 8 + p * 2;
          unsigned int u0 = (unsigned short)ldsT[j0 * 24 + dcol];
          unsigned int u1 = (unsigned short)ldsT[(j0 + 1) * 24 + dcol];
          pk.w[p] = u0 | (u1 << 16);
        }
        *(uint4*)(vW + ((size_t)head * 32 + gd) * 1024 + l0 + lg * 32 + s * 8) = pk.u4;
      }
    }
  }
}

// ---------------------------------------------------------------------------
// K3: MFMA attention, R16 hybrid. Grid 1024, 64 q/block (R13 structure).
// QK^T swapped: sacc[t] = mfma(Kfrag, Qfrag) -> lane holds S^T[key][q=m16].
// Kfrag: DIRECT global bf16x8 at kR[head][c*64+t*16+m16][quad*8], register
// double-buffered kfr[2][4] (prefetch c+1 during c; full unroll -> static idx).
// V: LDS double-buffered vt0/vt1 (R13-identical staging indexing), ONE barrier
// per chunk. P stays in registers (cvt_pk, kappa-permuted PV B-frag).
// LDS map (27136 B): vt0 [32][72]sh @0 (4608); vt1 @4608 (4608);
//   rhS f32 [32 j][68 r] @9216 (8704); rwS f32 [64 r][36 j] @17920 (9216).
//   prologue stgF f32 [63][36] (9072) aliases vt0/vt1 (dead before staging;
//   barrier between P3 reads and vt0 write).
// ---------------------------------------------------------------------------
__global__ __launch_bounds__(256) void attn_mfma_kernel(
    const bf16* __restrict__ qT, const bf16* __restrict__ kR, const bf16* __restrict__ vW,
    const float* __restrict__ krw, const float* __restrict__ krh,
    bf16* __restrict__ attL)
{
  __shared__ __align__(16) char smem[27136];
  short* vt0 = (short*)smem;            // [32 d][72]
  short* vt1 = (short*)(smem + 4608);
  float* stgF = (float*)smem;           // prologue alias
  float* rhS  = (float*)(smem + 9216);
  float* rwS  = (float*)(smem + 17920);

  const float L2E = 1.4426950408889634f;

  int tid = threadIdx.x;
  int lane = tid & 63, wave = tid >> 6;
  int m16 = lane & 15, quad = lane >> 4;
  int bid = blockIdx.x;
  // same head -> same blockIdx mod 8 -> same XCD (round-robin heuristic)
  int head = ((bid & 7) << 3) | ((bid >> 3) & 7);
  int qt = bid >> 6;                 // 0..15, 64 q rows per block
  int row0 = qt * 64;
  int b = head >> 3, h = head & 7;

  // V staging role + chunk-0 global prefetch
  int svd = tid >> 3, svk = tid & 7;         // V: 32 d x 8 key-segs of 8
  const bf16* vptr = vW + (size_t)head * 32768 + svd * 1024 + svk * 8;
  uint4 vreg = *(const uint4*)vptr;

  // per-thread prologue identity: row r (0..63), j-segment (0..3)
  int r = tid >> 2, jseg = tid & 3;
  float q32[32];
  {
    const bf16* qp = qT + ((size_t)head * 1024 + row0 + r) * 32;
#pragma unroll
    for (int s4 = 0; s4 < 4; ++s4) {
      uint4 u = ((const uint4*)qp)[s4];
      q32[s4 * 8 + 0] = blo(u.x); q32[s4 * 8 + 1] = bhi(u.x);
      q32[s4 * 8 + 2] = blo(u.y); q32[s4 * 8 + 3] = bhi(u.y);
      q32[s4 * 8 + 4] = blo(u.z); q32[s4 * 8 + 5] = bhi(u.z);
      q32[s4 * 8 + 6] = blo(u.w); q32[s4 * 8 + 7] = bhi(u.w);
    }
  }

  // ---- P0: stage krw f32 (stride 36) ----
  for (int i = tid; i < 504; i += 256) {
    int row = i >> 3, d0 = (i & 7) * 4;
    *(float4*)(stgF + row * 36 + d0) = *(const float4*)(krw + row * 32 + d0);
  }
  __syncthreads();

  // ---- P1: rwS[r][j] = log2e * (q[r] . krw[j - (r&31) + 31]) ----
  {
    int qi = r & 31;
#pragma unroll
    for (int jj2 = 0; jj2 < 2; ++jj2) {
      float rv[4];
#pragma unroll
      for (int jp = 0; jp < 4; ++jp) {
        int j = jseg * 8 + jj2 * 4 + jp;
        const float* kw = stgF + (j - qi + 31) * 36;
        float s1 = 0.f;
#pragma unroll
        for (int d4 = 0; d4 < 8; ++d4) {
          float4 kv = *(const float4*)(kw + d4 * 4);
          s1 += q32[d4 * 4 + 0] * kv.x + q32[d4 * 4 + 1] * kv.y +
                q32[d4 * 4 + 2] * kv.z + q32[d4 * 4 + 3] * kv.w;
        }
        rv[jp] = s1 * L2E;
      }
      *(float4*)(rwS + r * 36 + jseg * 8 + jj2 * 4) = make_float4(rv[0], rv[1], rv[2], rv[3]);
    }
  }
  __syncthreads();

  // ---- P2: stage krh over stgF ----
  for (int i = tid; i < 504; i += 256) {
    int row = i >> 3, d0 = (i & 7) * 4;
    *(float4*)(stgF + row * 36 + d0) = *(const float4*)(krh + row * 32 + d0);
  }
  __syncthreads();

  // ---- P3: rhS[j][r] = log2e * (q[r] . krh[j - qy + 31]) ----
  {
    int qy = qt * 2 + (r >> 5);
#pragma unroll
    for (int jj = 0; jj < 8; ++jj) {
      int j = jseg * 8 + jj;
      const float* kh = stgF + (j - qy + 31) * 36;
      float s2 = 0.f;
#pragma unroll
      for (int d4 = 0; d4 < 8; ++d4) {
        float4 kv = *(const float4*)(kh + d4 * 4);
        s2 += q32[d4 * 4 + 0] * kv.x + q32[d4 * 4 + 1] * kv.y +
              q32[d4 * 4 + 2] * kv.z + q32[d4 * 4 + 3] * kv.w;
      }
      rhS[j * 68 + r] = s2 * L2E;
    }
  }
  __syncthreads();   // rhS visible; stgF reads done -> vt0 alias now safe

  // ---- P4: Q fragment (B-operand) + chunk-invariant RW registers (row=q=m16)
  bf16x8 afrag = *(const bf16x8*)(
      qT + ((size_t)head * 1024 + row0 + wave * 16 + m16) * 32 + quad * 8);
  float rwreg[2][4];
  {
    float4 rw0 = *(const float4*)(rwS + (wave * 16 + m16) * 36 + quad * 4);
    float4 rw1 = *(const float4*)(rwS + (wave * 16 + m16) * 36 + 16 + quad * 4);
    rwreg[0][0] = rw0.x; rwreg[0][1] = rw0.y; rwreg[0][2] = rw0.z; rwreg[0][3] = rw0.w;
    rwreg[1][0] = rw1.x; rwreg[1][1] = rw1.y; rwreg[1][2] = rw1.z; rwreg[1][3] = rw1.w;
  }

  // stage chunk-0 V into vt0; prefetch chunk-1 V into vreg
  *(uint4*)(vt0 + svd * 72 + svk * 8) = vreg;
  vreg = *(const uint4*)(vptr + 64);

  // K fragment pointer (R15-proven) + chunk-0 register prefetch
  const bf16* kp = kR + (size_t)head * 32768 + m16 * 32 + quad * 8;   // +c*2048 +t*512
  uint4 kfr[2][4];
#pragma unroll
  for (int t = 0; t < 4; ++t) kfr[0][t] = *(const uint4*)(kp + t * 512);

  f32x4 oacc[2];
  oacc[0] = (f32x4){0.f, 0.f, 0.f, 0.f};
  oacc[1] = (f32x4){0.f, 0.f, 0.f, 0.f};
  float rsp = 0.f;

  __syncthreads();   // vt0 staging visible

#pragma unroll
  for (int c = 0; c < 16; ++c) {
    const int cur = c & 1, nxt = cur ^ 1;
    if (c < 15) {
      // stage chunk c+1 V into the buffer last read at iteration c-1 (safe:
      // end-of-(c-1) barrier ordered those reads before this write)
      short* vN = cur ? vt0 : vt1;
      *(uint4*)(vN + svd * 72 + svk * 8) = vreg;
      // register-prefetch chunk c+1 K (latency covered by this iteration)
#pragma unroll
      for (int t = 0; t < 4; ++t)
        kfr[nxt][t] = *(const uint4*)(kp + (c + 1) * 2048 + t * 512);
      if (c < 14) vreg = *(const uint4*)(vptr + (c + 2) * 64);
    }
    const short* vC = cur ? vt1 : vt0;

    // RH for this chunk (read-only LDS broadcast; key_y = c*2 + (t>>1))
    float rh0 = rhS[(c * 2 + 0) * 68 + wave * 16 + m16];
    float rh1 = rhS[(c * 2 + 1) * 68 + wave * 16 + m16];

    // QK^T swapped: A = K frag (rows=keys), B = Qfrag (cols=q)
    f32x4 sacc[4];
#pragma unroll
    for (int t = 0; t < 4; ++t) {
      union { uint4 u; bf16x8 v; } kf; kf.u = kfr[cur][t];
      f32x4 z = (f32x4){0.f, 0.f, 0.f, 0.f};
      sacc[t] = __builtin_amdgcn_mfma_f32_16x16x32_bf16(kf.v, afrag, z, 0, 0, 0);
    }

    // softmax numerators in-register (lane q = m16, key = t*16+quad*4+i)
    unsigned int pk[4][2];
#pragma unroll
    for (int t = 0; t < 4; ++t) {
      float rh = (t < 2) ? rh0 : rh1;
      float e0 = exp2_f(fmaf(sacc[t][0], L2E, rwreg[t & 1][0] + rh));
      float e1 = exp2_f(fmaf(sacc[t][1], L2E, rwreg[t & 1][1] + rh));
      float e2 = exp2_f(fmaf(sacc[t][2], L2E, rwreg[t & 1][2] + rh));
      float e3 = exp2_f(fmaf(sacc[t][3], L2E, rwreg[t & 1][3] + rh));
      rsp += (e0 + e1) + (e2 + e3);
      pk[t][0] = cvt_pk_bf16(e0, e1);
      pk[t][1] = cvt_pk_bf16(e2, e3);
    }

    // PV: O^T = mfma(Vfrag, P^T). kappa = ks*32 + (j>>2)*16 + quad*4 + (j&3).
#pragma unroll
    for (int ks = 0; ks < 2; ++ks) {
      union { unsigned int w[4]; bf16x8 v; } pf;
      pf.w[0] = pk[2 * ks][0];     pf.w[1] = pk[2 * ks][1];
      pf.w[2] = pk[2 * ks + 1][0]; pf.w[3] = pk[2 * ks + 1][1];
#pragma unroll
      for (int dt = 0; dt < 2; ++dt) {
        const short* vb = vC + (dt * 16 + m16) * 72 + ks * 32 + quad * 4;
        union { uint2 u[2]; bf16x8 v; } vf;
        vf.u[0] = *(const uint2*)(vb);
        vf.u[1] = *(const uint2*)(vb + 16);
        oacc[dt] = __builtin_amdgcn_mfma_f32_16x16x32_bf16(vf.v, pf.v, oacc[dt], 0, 0, 0);
      }
    }

    if (c < 15) __syncthreads();   // chunk c+1 staging visible; one barrier/chunk
  }

  // ---- epilogue: reduce row-sums across quads, normalize, store ----
  rsp += __shfl_xor(rsp, 16, 64);
  rsp += __shfl_xor(rsp, 32, 64);
  float invs = 1.0f / rsp;
  int grow = row0 + wave * 16 + m16;
#pragma unroll
  for (int dt = 0; dt < 2; ++dt) {
    uint2 st;
    st.x = cvt_pk_bf16(oacc[dt][0] * invs, oacc[dt][1] * invs);
    st.y = cvt_pk_bf16(oacc[dt][2] * invs, oacc[dt][3] * invs);
    *(uint2*)(attL + ((size_t)b * 1024 + grow) * 256 + h * 32 + dt * 16 + quad * 4) = st;
  }
}

// ---------------------------------------------------------------------------
// K4: attnout 1x1 conv as MFMA GEMM 256 x 1024 x 256 per batch. (R6 version)
// Runs last; overwrites the d_out ch256+ regions that hosted wo_bf.
// ---------------------------------------------------------------------------
__global__ __launch_bounds__(256) void attnout_mfma_kernel(
    const bf16* __restrict__ attL, const float* __restrict__ w, const float* __restrict__ bias,
    float* __restrict__ out)
{
  __shared__ __align__(16) short smem[13824];
  short* aS = smem;            // [64 co][72]
  short* bS = smem + 4608;     // [128 l][72]

  int tid = threadIdx.x, lane = tid & 63, wave = tid >> 6;
  int m16 = lane & 15, quad = lane >> 4;
  int l0 = blockIdx.x * 128;
  int cotile = blockIdx.y;
  int b = blockIdx.z;
  int cbase = cotile * 64;

  f32x4 acc[8];
#pragma unroll
  for (int t = 0; t < 8; ++t) acc[t] = (f32x4){0.f, 0.f, 0.f, 0.f};

  for (int ck = 0; ck < 4; ++ck) {
    __syncthreads();
#pragma unroll
    for (int r = 0; r < 4; ++r) {
      int u = r * 256 + tid;
      int c = u >> 4, s4 = u & 15;
      float4 v = *(const float4*)(w + (size_t)(cbase + c) * 256 + ck * 64 + s4 * 4);
      unsigned int p0 = (unsigned int)f2bfbits(v.x) | ((unsigned int)f2bfbits(v.y) << 16);
      unsigned int p1 = (unsigned int)f2bfbits(v.z) | ((unsigned int)f2bfbits(v.w) << 16);
      uint2 u2; u2.x = p0; u2.y = p1;
      *(uint2*)(aS + c * 72 + s4 * 4) = u2;
    }
#pragma unroll
    for (int r = 0; r < 4; ++r) {
      int u = r * 256 + tid;
      int l = u >> 3, seg = u & 7;
      *(uint4*)(bS + l * 72 + seg * 8) =
          *(const uint4*)(attL + ((size_t)(b * 1024) + l0 + l) * 256 + ck * 64 + seg * 8);
    }
    __syncthreads();
#pragma unroll
    for (int ks = 0; ks < 2; ++ks) {
      bf16x8 af = *(const bf16x8*)(aS + (wave * 16 + m16) * 72 + ks * 32 + quad * 8);
#pragma unroll
      for (int t = 0; t < 8; ++t) {
        bf16x8 bf = *(const bf16x8*)(bS + (t * 16 + m16) * 72 + ks * 32 + quad * 8);
        acc[t] = __builtin_amdgcn_mfma_f32_16x16x32_bf16(af, bf, acc[t], 0, 0, 0);
      }
    }
  }

  int co = cbase + wave * 16 + quad * 4;
#pragma unroll
  for (int i = 0; i < 4; ++i) {
    float bv = bias[co + i];
    size_t obase = ((size_t)(b * 512) + 256 + co + i) * 1024 + l0;
#pragma unroll
    for (int t = 0; t < 8; ++t)
      out[obase + t * 16 + m16] = acc[t][i] + bv;
  }
}

// ---------------------------------------------------------------------------
extern "C" void kernel_launch(void* const* d_in, const int* in_sizes, int n_in,
                              void* d_out, int out_size, void* d_ws, size_t ws_size,
                              hipStream_t stream) {
  const float* x      = (const float*)d_in[0];
  const float* w_qkv  = (const float*)d_in[1];
  const float* b_qkv  = (const float*)d_in[2];
  const float* w_attn = (const float*)d_in[3];
  const float* b_attn = (const float*)d_in[4];
  const float* w_out  = (const float*)d_in[5];
  const float* b_out  = (const float*)d_in[6];
  const float* krw    = (const float*)d_in[7];
  const float* krh    = (const float*)d_in[8];
  float* out = (float*)d_out;

  bf16* ws    = (bf16*)d_ws;
  bf16* xT    = ws;                 // [0, 2,097,152)  read by fused conv3+qkv
  bf16* attL  = ws;                 // alias of xT     (attn -> attnout, after fused)
  bf16* qT    = ws + 2097152;       // [2,097,152, 4,194,304)
  bf16* kR    = ws + 4194304;       // [4,194,304, 6,291,456)
  bf16* vW    = ws + 6291456;       // [6,291,456, 8,388,608)  exact 16 MB fit

  // wo_bf in d_out's attention half (dead until attnout overwrites it)
  bf16* wob0 = (bf16*)(out + (size_t)(0 * 512 + 256) * 1024);
  bf16* wob1 = (bf16*)(out + (size_t)(1 * 512 + 256) * 1024);

  prep_kernel<<<dim3(2084), 256, 0, stream>>>(x, w_out, xT, wob0, wob1);
  convqkv_kernel<<<dim3(1024), 256, 0, stream>>>(xT, wob0, wob1, b_out, out,
                                                 w_qkv, b_qkv, qT, kR, vW);
  attn_mfma_kernel<<<dim3(1024), 256, 0, stream>>>(qT, kR, vW, krw, krh, attL);
  attnout_mfma_kernel<<<dim3(8, 4, 8), 256, 0, stream>>>(attL, w_attn, b_attn, out);
}

// Round 5
// 147.779 us; speedup vs baseline: 1.3130x; 1.1150x over previous
//
#include <hip/hip_runtime.h>
#include <hip/hip_bf16.h>

// AttentionConv2d: B=8, C_IN=256, H=W=32 (HW=1024), DK=DV=256, NH=8, DKH=DVH=32,
// C_OUT=512, 3x3 conv pad=1. fp32 storage in/out; bf16 intermediates + MFMA.
//
// Workspace (bf16 elements, EXACTLY 16 MB):
//   xT    [8 b][1024 l][256 ci]  @ 0          read by fused conv3+qkv
//   attL  [8 b][1024 l][256 ch]  @ 0          alias of xT (attn writes after fused done)
//   qT    [64 head][1024][32]    @ 2,097,152
//   kR    [64 head][1024][32]    @ 4,194,304
//   vF    [64 head][16 c][4 q][64 lane][8]  @ 6,291,456   (PV-fragment order)
// prep -> convqkv(fused) -> attn -> attnout.
// R17: V stored in FRAGMENT ORDER by convqkv (vF): for chunk c, tile q=dt*2+ks,
// lane (quad*16+m16), the 8 bf16 {key = c*64+ks*32+quad*4+{0..3,16..19}} of
// row d=dt*16+m16 are contiguous -> attn's PV A-frag is ONE coalesced 16B/lane
// load. attn K-loop: zero barriers, zero K/V LDS (K direct per R15-proven
// addresses; V direct via vF). Loop kept rolled (#pragma unroll 1) to hold
// VGPR ~90 (R16's 164-VGPR unroll collapse). LDS: prologue rw/rh tables only.

typedef __hip_bfloat16 bf16;
typedef __attribute__((ext_vector_type(8))) short bf16x8;
typedef __attribute__((ext_vector_type(4))) float f32x4;

__device__ __forceinline__ float blo(unsigned int v) { return __uint_as_float(v << 16); }
__device__ __forceinline__ float bhi(unsigned int v) { return __uint_as_float(v & 0xffff0000u); }
__device__ __forceinline__ unsigned short f2bfbits(float f) {
  union { bf16 h; unsigned short u; } cv; cv.h = __float2bfloat16(f); return cv.u;
}
// v_cvt_pk_bf16_f32: dst.lo = bf16(lo), dst.hi = bf16(hi). RNE, 1 VALU op.
__device__ __forceinline__ unsigned int cvt_pk_bf16(float lo, float hi) {
  unsigned int r;
  asm("v_cvt_pk_bf16_f32 %0, %1, %2" : "=v"(r) : "v"(lo), "v"(hi));
  return r;
}
__device__ __forceinline__ float exp2_f(float x) {
#if __has_builtin(__builtin_amdgcn_exp2f)
  return __builtin_amdgcn_exp2f(x);
#else
  return exp2f(x);
#endif
}

// ---------------------------------------------------------------------------
// K0: prep — xT transpose to bf16 + w_out bf16 chunk-blocked into wob0/wob1.
// blocks 0..2047: xT; 2048..2083: w_out. grid 2084.
// ---------------------------------------------------------------------------
__global__ __launch_bounds__(256) void prep_kernel(
    const float* __restrict__ x, const float* __restrict__ wout,
    bf16* __restrict__ xT, bf16* __restrict__ wob0, bf16* __restrict__ wob1)
{
  int bid = blockIdx.x, tid = threadIdx.x;
  if (bid < 2048) {
    __shared__ float t[32 * 33];
    int b = bid >> 8, rem = bid & 255;
    int ci0 = (rem >> 5) * 32, l0 = (rem & 31) * 32;
    {
      int ciL = tid >> 3, lL4 = (tid & 7) * 4;
      float4 v = *(const float4*)(x + (size_t)(b * 256 + ci0 + ciL) * 1024 + l0 + lL4);
      t[ciL * 33 + lL4 + 0] = v.x; t[ciL * 33 + lL4 + 1] = v.y;
      t[ciL * 33 + lL4 + 2] = v.z; t[ciL * 33 + lL4 + 3] = v.w;
    }
    __syncthreads();
    {
      int lL = tid >> 3, cS = (tid & 7) * 4;
      unsigned int p0 = (unsigned int)f2bfbits(t[(cS + 0) * 33 + lL]) |
                        ((unsigned int)f2bfbits(t[(cS + 1) * 33 + lL]) << 16);
      unsigned int p1 = (unsigned int)f2bfbits(t[(cS + 2) * 33 + lL]) |
                        ((unsigned int)f2bfbits(t[(cS + 3) * 33 + lL]) << 16);
      uint2 u2; u2.x = p0; u2.y = p1;
      *(uint2*)(xT + ((size_t)(b * 1024) + l0 + lL) * 256 + ci0 + cS) = u2;
    }
  } else {
    int t0 = (bid - 2048) * 256 + tid;       // 0..9215
#pragma unroll
    for (int s = 0; s < 8; ++s) {
      int u = s * 9216 + t0;                 // dst uint4 index 0..73727
      int chunkblk = u / 2304;
      int within = u - chunkblk * 2304;
      int co63 = within / 36;
      int r = within - co63 * 36;            // kidx*4 + cig
      int kidx = r >> 2, cig = r & 3;
      int co = (chunkblk >> 3) * 64 + co63;
      int ci = (chunkblk & 7) * 32 + cig * 8;
      union { unsigned short h[8]; uint4 u4; } pk;
#pragma unroll
      for (int j = 0; j < 8; ++j)
        pk.h[j] = f2bfbits(wout[(size_t)(co * 256 + ci + j) * 9 + kidx]);
      bf16* dst = (chunkblk < 28) ? (wob0 + (size_t)chunkblk * 18432)
                                  : (wob1 + (size_t)(chunkblk - 28) * 18432);
      *(uint4*)(dst + (size_t)within * 8) = pk.u4;
    }
  }
}

// ---------------------------------------------------------------------------
// K1 (fused): blocks 0..255 = conv3 (3x3, MFMA shift-GEMM, prepacked weights);
// 256..1023 = qkv GEMM. Both only read xT -> co-resident, mutual latency hiding.
// R17: V epilogue writes fragment-ordered vF (see header).
// ---------------------------------------------------------------------------
__global__ __launch_bounds__(256) void convqkv_kernel(
    const bf16* __restrict__ xT,
    const bf16* __restrict__ wob0, const bf16* __restrict__ wob1,
    const float* __restrict__ b_out, float* __restrict__ out,
    const float* __restrict__ wq, const float* __restrict__ b_qkv,
    bf16* __restrict__ qT, bf16* __restrict__ kR, bf16* __restrict__ vW)
{
  __shared__ __align__(16) short smem[27104];
  int tid = threadIdx.x, lane = tid & 63, wave = tid >> 6;
  int m16 = lane & 15, quad = lane >> 4;

  if (blockIdx.x < 256) {
    short* wS = smem;            // [64 co][296]
    short* xS = smem + 18944;    // [6 rows][34 cols][40]
    int bid = blockIdx.x;
    int rc = bid & 7, cotile = (bid >> 3) & 3, b = bid >> 5;
    int y0 = rc * 4;

    f32x4 acc[8];
#pragma unroll
    for (int t = 0; t < 8; ++t) acc[t] = (f32x4){0.f, 0.f, 0.f, 0.f};

    for (int ck = 0; ck < 8; ++ck) {
      __syncthreads();
      int cb = cotile * 8 + ck;
      const bf16* wbase = (cb < 28) ? (wob0 + (size_t)cb * 18432)
                                    : (wob1 + (size_t)(cb - 28) * 18432);
#pragma unroll
      for (int r = 0; r < 9; ++r) {
        int u = r * 256 + tid;
        *(uint4*)(wS + (u / 36) * 296 + (u % 36) * 8) = *(const uint4*)(wbase + (size_t)u * 8);
      }
#pragma unroll
      for (int r = 0; r < 3; ++r) {
        int u = r * 256 + tid;
        int pos = u >> 2, seg = u & 3;
        int row = pos >> 5, col = pos & 31;
        int gy = y0 - 1 + row;
        uint4 val = make_uint4(0u, 0u, 0u, 0u);
        if (gy >= 0 && gy < 32)
          val = *(const uint4*)(xT + ((size_t)(b * 1024) + gy * 32 + col) * 256 + ck * 32 + seg * 8);
        *(uint4*)(xS + (row * 34 + col + 1) * 40 + seg * 8) = val;
      }
      if (tid < 48) {
        int pos = tid >> 2, seg = tid & 3;
        int row = pos >> 1, side = pos & 1;
        *(uint4*)(xS + (row * 34 + side * 33) * 40 + seg * 8) = make_uint4(0u, 0u, 0u, 0u);
      }
      __syncthreads();
#pragma unroll
      for (int kidx = 0; kidx < 9; ++kidx) {
        int dy = kidx / 3, dx = kidx - dy * 3;
        bf16x8 af = *(const bf16x8*)(wS + (wave * 16 + m16) * 296 + kidx * 32 + quad * 8);
#pragma unroll
        for (int t = 0; t < 8; ++t) {
          int row = (t >> 1) + dy;
          int col = (t & 1) * 16 + m16 + dx;
          bf16x8 bf = *(const bf16x8*)(xS + (row * 34 + col) * 40 + quad * 8);
          acc[t] = __builtin_amdgcn_mfma_f32_16x16x32_bf16(af, bf, acc[t], 0, 0, 0);
        }
      }
    }

    int cob = cotile * 64 + wave * 16 + quad * 4;
#pragma unroll
    for (int i = 0; i < 4; ++i) {
      float bv = b_out[cob + i];
#pragma unroll
      for (int t = 0; t < 8; ++t) {
        int y = y0 + (t >> 1), xc = (t & 1) * 16 + m16;
        out[((size_t)(b * 512) + cob + i) * 1024 + y * 32 + xc] = acc[t][i] + bv;
      }
    }
  } else {
    short* aS = smem;            // [64][72]
    short* bS = smem + 4608;     // [128][72]
    int bid2 = blockIdx.x - 256;
    int ltile = bid2 & 7;
    int rest = bid2 >> 3;
    int ctile = rest % 12;
    int b = rest / 12;
    int l0 = ltile * 128;
    int cbase = ctile * 64;

    f32x4 acc[8];
#pragma unroll
    for (int t = 0; t < 8; ++t) acc[t] = (f32x4){0.f, 0.f, 0.f, 0.f};

    for (int ck = 0; ck < 4; ++ck) {
      __syncthreads();
#pragma unroll
      for (int r = 0; r < 4; ++r) {
        int u = r * 256 + tid;
        int c = u >> 4, s4 = u & 15;
        float4 v = *(const float4*)(wq + (size_t)(cbase + c) * 256 + ck * 64 + s4 * 4);
        unsigned int p0 = (unsigned int)f2bfbits(v.x) | ((unsigned int)f2bfbits(v.y) << 16);
        unsigned int p1 = (unsigned int)f2bfbits(v.z) | ((unsigned int)f2bfbits(v.w) << 16);
        uint2 u2; u2.x = p0; u2.y = p1;
        *(uint2*)(aS + c * 72 + s4 * 4) = u2;
      }
#pragma unroll
      for (int r = 0; r < 4; ++r) {
        int u = r * 256 + tid;
        int l = u >> 3, seg = u & 7;
        *(uint4*)(bS + l * 72 + seg * 8) =
            *(const uint4*)(xT + ((size_t)(b * 1024) + l0 + l) * 256 + ck * 64 + seg * 8);
      }
      __syncthreads();
#pragma unroll
      for (int ks = 0; ks < 2; ++ks) {
        bf16x8 af = *(const bf16x8*)(aS + (wave * 16 + m16) * 72 + ks * 32 + quad * 8);
#pragma unroll
        for (int t = 0; t < 8; ++t) {
          bf16x8 bf = *(const bf16x8*)(bS + (t * 16 + m16) * 72 + ks * 32 + quad * 8);
          acc[t] = __builtin_amdgcn_mfma_f32_16x16x32_bf16(af, bf, acc[t], 0, 0, 0);
        }
      }
    }

    __syncthreads();
    short* ldsT = smem + wave * 3072;
    int cb = cbase + wave * 16;
    bool isq = (ctile < 4);
    float bv[4];
#pragma unroll
    for (int i = 0; i < 4; ++i) bv[i] = b_qkv[cb + quad * 4 + i];
#pragma unroll
    for (int t = 0; t < 8; ++t) {
#pragma unroll
      for (int i = 0; i < 4; ++i) {
        float v = acc[t][i] + bv[i];
        if (isq) v *= 0.17677669529663689f;  // 32^-0.5, pre-rel-logits
        ldsT[(t * 16 + m16) * 24 + quad * 4 + i] = (short)f2bfbits(v);
      }
    }
    if (ctile < 8) {
      bf16* dst = isq ? qT : kR;
      int coff = isq ? cb : cb - 256;
#pragma unroll
      for (int rep = 0; rep < 4; ++rep) {
        int u = rep * 64 + lane;
        int l = u >> 1, half = u & 1;
        int c0 = coff + half * 8;
        int head = b * 8 + (c0 >> 5), d0 = c0 & 31;
        *(uint4*)(dst + ((size_t)head * 1024 + l0 + l) * 32 + d0) =
            *(const uint4*)(ldsT + l * 24 + half * 8);
      }
    } else {
      // R17: fragment-ordered vF writes.
      // thread identity: d = gd (fixed), keys = l0 + lg*32 + s*8 + p*2 + e.
      // vF elem = head*32768 + c*2048 + (dt*2+ks)*512 + (quad'*16+m16')*8 + j
      //   c = ltile*2 + (lg>>1), ks = lg&1, dt = gd>>4, m16' = gd&15,
      //   quad' = (s&1)*2 + (p>>1), j0 = (p&1)*2 + (s>>1)*4 (e=0,1 consecutive).
      int dcol = lane >> 2, lg = lane & 3;
      int c2 = (cb - 512) + dcol;
      int head = b * 8 + (c2 >> 5), gd = c2 & 31;
      int dt = gd >> 4, m16v = gd & 15;
      int cch = ltile * 2 + (lg >> 1);
      int ksv = lg & 1;
      bf16* vbase = vW + (size_t)head * 32768 + cch * 2048 + (dt * 2 + ksv) * 512 + m16v * 8;
#pragma unroll
      for (int s = 0; s < 4; ++s) {
#pragma unroll
        for (int p = 0; p < 4; ++p) {
          int j0 = lg * 32 + s * 8 + p * 2;
          unsigned int u0 = (unsigned short)ldsT[j0 * 24 + dcol];
          unsigned int u1 = (unsigned short)ldsT[(j0 + 1) * 24 + dcol];
          unsigned int w = u0 | (u1 << 16);
          int quadp = (s & 1) * 2 + (p >> 1);
          int jj = (p & 1) * 2 + (s >> 1) * 4;
          *(unsigned int*)(vbase + quadp * 128 + jj) = w;
        }
      }
    }
  }
}

// ---------------------------------------------------------------------------
// K3: MFMA attention, R17. Grid 1024, 64 q/block (R13 structure). ZERO in-loop
// barriers, zero K/V LDS. QK^T swapped: sacc[t] = mfma(Kfrag, Qfrag) -> lane
// holds S^T[key][q=m16]. Kfrag: direct global bf16x8 at
// kR[head][c*64+t*16+m16][quad*8] (R15-proven). Vfrag: ONE coalesced uint4 at
// vF[head] + c*2048 + (dt*2+ks)*512 + lane*8 (fragment-ordered by convqkv).
// P = exp2(fma(S,L2E,rw+rh)) packed via cvt_pk stays in registers (PV B-frag
// under kappa). Loop rolled (#pragma unroll 1) to keep VGPR low.
// LDS map (27648 B): stgF f32 [63][36] @0 (9072, prologue scratch);
//   rhS f32 [32 j][68 r] @9728; rwS f32 [64 r][36 j] @18432. log2e pre-folded.
// ---------------------------------------------------------------------------
__global__ __launch_bounds__(256) void attn_mfma_kernel(
    const bf16* __restrict__ qT, const bf16* __restrict__ kR, const bf16* __restrict__ vW,
    const float* __restrict__ krw, const float* __restrict__ krh,
    bf16* __restrict__ attL)
{
  __shared__ __align__(16) char smem[27648];
  float* stgF = (float*)smem;
  float* rhS  = (float*)(smem + 9728);
  float* rwS  = (float*)(smem + 18432);

  const float L2E = 1.4426950408889634f;

  int tid = threadIdx.x;
  int lane = tid & 63, wave = tid >> 6;
  int m16 = lane & 15, quad = lane >> 4;
  int bid = blockIdx.x;
  // same head -> same blockIdx mod 8 -> same XCD (round-robin heuristic)
  int head = ((bid & 7) << 3) | ((bid >> 3) & 7);
  int qt = bid >> 6;                 // 0..15, 64 q rows per block
  int row0 = qt * 64;
  int b = head >> 3, h = head & 7;

  // per-thread prologue identity: row r (0..63), j-segment (0..3)
  int r = tid >> 2, jseg = tid & 3;
  float q32[32];
  {
    const bf16* qp = qT + ((size_t)head * 1024 + row0 + r) * 32;
#pragma unroll
    for (int s4 = 0; s4 < 4; ++s4) {
      uint4 u = ((const uint4*)qp)[s4];
      q32[s4 * 8 + 0] = blo(u.x); q32[s4 * 8 + 1] = bhi(u.x);
      q32[s4 * 8 + 2] = blo(u.y); q32[s4 * 8 + 3] = bhi(u.y);
      q32[s4 * 8 + 4] = blo(u.z); q32[s4 * 8 + 5] = bhi(u.z);
      q32[s4 * 8 + 6] = blo(u.w); q32[s4 * 8 + 7] = bhi(u.w);
    }
  }

  // ---- P0: stage krw f32 (stride 36) ----
  for (int i = tid; i < 504; i += 256) {
    int row = i >> 3, d0 = (i & 7) * 4;
    *(float4*)(stgF + row * 36 + d0) = *(const float4*)(krw + row * 32 + d0);
  }
  __syncthreads();

  // ---- P1: rwS[r][j] = log2e * (q[r] . krw[j - (r&31) + 31]) ----
  {
    int qi = r & 31;
#pragma unroll
    for (int jj2 = 0; jj2 < 2; ++jj2) {
      float rv[4];
#pragma unroll
      for (int jp = 0; jp < 4; ++jp) {
        int j = jseg * 8 + jj2 * 4 + jp;
        const float* kw = stgF + (j - qi + 31) * 36;
        float s1 = 0.f;
#pragma unroll
        for (int d4 = 0; d4 < 8; ++d4) {
          float4 kv = *(const float4*)(kw + d4 * 4);
          s1 += q32[d4 * 4 + 0] * kv.x + q32[d4 * 4 + 1] * kv.y +
                q32[d4 * 4 + 2] * kv.z + q32[d4 * 4 + 3] * kv.w;
        }
        rv[jp] = s1 * L2E;
      }
      *(float4*)(rwS + r * 36 + jseg * 8 + jj2 * 4) = make_float4(rv[0], rv[1], rv[2], rv[3]);
    }
  }
  __syncthreads();

  // ---- P2: stage krh over stgF ----
  for (int i = tid; i < 504; i += 256) {
    int row = i >> 3, d0 = (i & 7) * 4;
    *(float4*)(stgF + row * 36 + d0) = *(const float4*)(krh + row * 32 + d0);
  }
  __syncthreads();

  // ---- P3: rhS[j][r] = log2e * (q[r] . krh[j - qy + 31]) ----
  {
    int qy = qt * 2 + (r >> 5);
#pragma unroll
    for (int jj = 0; jj < 8; ++jj) {
      int j = jseg * 8 + jj;
      const float* kh = stgF + (j - qy + 31) * 36;
      float s2 = 0.f;
#pragma unroll
      for (int d4 = 0; d4 < 8; ++d4) {
        float4 kv = *(const float4*)(kh + d4 * 4);
        s2 += q32[d4 * 4 + 0] * kv.x + q32[d4 * 4 + 1] * kv.y +
              q32[d4 * 4 + 2] * kv.z + q32[d4 * 4 + 3] * kv.w;
      }
      rhS[j * 68 + r] = s2 * L2E;
    }
  }
  __syncthreads();   // rhS/rwS read-only from here; NO more barriers

  // ---- P4: Q fragment (B-operand) + chunk-invariant RW registers (row=q=m16)
  bf16x8 afrag = *(const bf16x8*)(
      qT + ((size_t)head * 1024 + row0 + wave * 16 + m16) * 32 + quad * 8);
  float rwreg[2][4];
  {
    float4 rw0 = *(const float4*)(rwS + (wave * 16 + m16) * 36 + quad * 4);
    float4 rw1 = *(const float4*)(rwS + (wave * 16 + m16) * 36 + 16 + quad * 4);
    rwreg[0][0] = rw0.x; rwreg[0][1] = rw0.y; rwreg[0][2] = rw0.z; rwreg[0][3] = rw0.w;
    rwreg[1][0] = rw1.x; rwreg[1][1] = rw1.y; rwreg[1][2] = rw1.z; rwreg[1][3] = rw1.w;
  }

  // per-lane global fragment pointers
  const bf16* kp = kR + (size_t)head * 32768 + m16 * 32 + quad * 8;   // +c*2048 +t*512
  const bf16* vp = vW + (size_t)head * 32768 + lane * 8;              // +c*2048 +(dt*2+ks)*512

  f32x4 oacc[2];
  oacc[0] = (f32x4){0.f, 0.f, 0.f, 0.f};
  oacc[1] = (f32x4){0.f, 0.f, 0.f, 0.f};
  float rsp = 0.f;

#pragma unroll 1
  for (int c = 0; c < 16; ++c) {
    // issue all 8 global fragment loads up front (latency overlaps exp below)
    union { uint4 u; bf16x8 v; } kf[4], vf[4];
#pragma unroll
    for (int t = 0; t < 4; ++t)
      kf[t].u = *(const uint4*)(kp + c * 2048 + t * 512);
#pragma unroll
    for (int q = 0; q < 4; ++q)         // q = dt*2 + ks
      vf[q].u = *(const uint4*)(vp + c * 2048 + q * 512);

    // RH for this chunk (read-only LDS broadcast; key_y = c*2 + (t>>1))
    float rh0 = rhS[(c * 2 + 0) * 68 + wave * 16 + m16];
    float rh1 = rhS[(c * 2 + 1) * 68 + wave * 16 + m16];

    // QK^T swapped: A = K frag (rows=keys), B = Qfrag (cols=q)
    f32x4 sacc[4];
#pragma unroll
    for (int t = 0; t < 4; ++t) {
      f32x4 z = (f32x4){0.f, 0.f, 0.f, 0.f};
      sacc[t] = __builtin_amdgcn_mfma_f32_16x16x32_bf16(kf[t].v, afrag, z, 0, 0, 0);
    }

    // softmax numerators in-register (lane q = m16, key = t*16+quad*4+i)
    unsigned int pk[4][2];
#pragma unroll
    for (int t = 0; t < 4; ++t) {
      float rh = (t < 2) ? rh0 : rh1;
      float e0 = exp2_f(fmaf(sacc[t][0], L2E, rwreg[t & 1][0] + rh));
      float e1 = exp2_f(fmaf(sacc[t][1], L2E, rwreg[t & 1][1] + rh));
      float e2 = exp2_f(fmaf(sacc[t][2], L2E, rwreg[t & 1][2] + rh));
      float e3 = exp2_f(fmaf(sacc[t][3], L2E, rwreg[t & 1][3] + rh));
      rsp += (e0 + e1) + (e2 + e3);
      pk[t][0] = cvt_pk_bf16(e0, e1);
      pk[t][1] = cvt_pk_bf16(e2, e3);
    }

    // PV: O^T = mfma(Vfrag, P^T). kappa = ks*32 + (j>>2)*16 + quad*4 + (j&3).
#pragma unroll
    for (int ks = 0; ks < 2; ++ks) {
      union { unsigned int w[4]; bf16x8 v; } pf;
      pf.w[0] = pk[2 * ks][0];     pf.w[1] = pk[2 * ks][1];
      pf.w[2] = pk[2 * ks + 1][0]; pf.w[3] = pk[2 * ks + 1][1];
#pragma unroll
      for (int dt = 0; dt < 2; ++dt) {
        oacc[dt] = __builtin_amdgcn_mfma_f32_16x16x32_bf16(vf[dt * 2 + ks].v, pf.v, oacc[dt], 0, 0, 0);
      }
    }
  }

  // ---- epilogue: reduce row-sums across quads, normalize, store ----
  rsp += __shfl_xor(rsp, 16, 64);
  rsp += __shfl_xor(rsp, 32, 64);
  float invs = 1.0f / rsp;
  int grow = row0 + wave * 16 + m16;
#pragma unroll
  for (int dt = 0; dt < 2; ++dt) {
    uint2 st;
    st.x = cvt_pk_bf16(oacc[dt][0] * invs, oacc[dt][1] * invs);
    st.y = cvt_pk_bf16(oacc[dt][2] * invs, oacc[dt][3] * invs);
    *(uint2*)(attL + ((size_t)b * 1024 + grow) * 256 + h * 32 + dt * 16 + quad * 4) = st;
  }
}

// ---------------------------------------------------------------------------
// K4: attnout 1x1 conv as MFMA GEMM 256 x 1024 x 256 per batch. (R6 version)
// Runs last; overwrites the d_out ch256+ regions that hosted wo_bf.
// ---------------------------------------------------------------------------
__global__ __launch_bounds__(256) void attnout_mfma_kernel(
    const bf16* __restrict__ attL, const float* __restrict__ w, const float* __restrict__ bias,
    float* __restrict__ out)
{
  __shared__ __align__(16) short smem[13824];
  short* aS = smem;            // [64 co][72]
  short* bS = smem + 4608;     // [128 l][72]

  int tid = threadIdx.x, lane = tid & 63, wave = tid >> 6;
  int m16 = lane & 15, quad = lane >> 4;
  int l0 = blockIdx.x * 128;
  int cotile = blockIdx.y;
  int b = blockIdx.z;
  int cbase = cotile * 64;

  f32x4 acc[8];
#pragma unroll
  for (int t = 0; t < 8; ++t) acc[t] = (f32x4){0.f, 0.f, 0.f, 0.f};

  for (int ck = 0; ck < 4; ++ck) {
    __syncthreads();
#pragma unroll
    for (int r = 0; r < 4; ++r) {
      int u = r * 256 + tid;
      int c = u >> 4, s4 = u & 15;
      float4 v = *(const float4*)(w + (size_t)(cbase + c) * 256 + ck * 64 + s4 * 4);
      unsigned int p0 = (unsigned int)f2bfbits(v.x) | ((unsigned int)f2bfbits(v.y) << 16);
      unsigned int p1 = (unsigned int)f2bfbits(v.z) | ((unsigned int)f2bfbits(v.w) << 16);
      uint2 u2; u2.x = p0; u2.y = p1;
      *(uint2*)(aS + c * 72 + s4 * 4) = u2;
    }
#pragma unroll
    for (int r = 0; r < 4; ++r) {
      int u = r * 256 + tid;
      int l = u >> 3, seg = u & 7;
      *(uint4*)(bS + l * 72 + seg * 8) =
          *(const uint4*)(attL + ((size_t)(b * 1024) + l0 + l) * 256 + ck * 64 + seg * 8);
    }
    __syncthreads();
#pragma unroll
    for (int ks = 0; ks < 2; ++ks) {
      bf16x8 af = *(const bf16x8*)(aS + (wave * 16 + m16) * 72 + ks * 32 + quad * 8);
#pragma unroll
      for (int t = 0; t < 8; ++t) {
        bf16x8 bf = *(const bf16x8*)(bS + (t * 16 + m16) * 72 + ks * 32 + quad * 8);
        acc[t] = __builtin_amdgcn_mfma_f32_16x16x32_bf16(af, bf, acc[t], 0, 0, 0);
      }
    }
  }

  int co = cbase + wave * 16 + quad * 4;
#pragma unroll
  for (int i = 0; i < 4; ++i) {
    float bv = bias[co + i];
    size_t obase = ((size_t)(b * 512) + 256 + co + i) * 1024 + l0;
#pragma unroll
    for (int t = 0; t < 8; ++t)
      out[obase + t * 16 + m16] = acc[t][i] + bv;
  }
}

// ---------------------------------------------------------------------------
extern "C" void kernel_launch(void* const* d_in, const int* in_sizes, int n_in,
                              void* d_out, int out_size, void* d_ws, size_t ws_size,
                              hipStream_t stream) {
  const float* x      = (const float*)d_in[0];
  const float* w_qkv  = (const float*)d_in[1];
  const float* b_qkv  = (const float*)d_in[2];
  const float* w_attn = (const float*)d_in[3];
  const float* b_attn = (const float*)d_in[4];
  const float* w_out  = (const float*)d_in[5];
  const float* b_out  = (const float*)d_in[6];
  const float* krw    = (const float*)d_in[7];
  const float* krh    = (const float*)d_in[8];
  float* out = (float*)d_out;

  bf16* ws    = (bf16*)d_ws;
  bf16* xT    = ws;                 // [0, 2,097,152)  read by fused conv3+qkv
  bf16* attL  = ws;                 // alias of xT     (attn -> attnout, after fused)
  bf16* qT    = ws + 2097152;       // [2,097,152, 4,194,304)
  bf16* kR    = ws + 4194304;       // [4,194,304, 6,291,456)
  bf16* vF    = ws + 6291456;       // [6,291,456, 8,388,608)  fragment-ordered V

  // wo_bf in d_out's attention half (dead until attnout overwrites it)
  bf16* wob0 = (bf16*)(out + (size_t)(0 * 512 + 256) * 1024);
  bf16* wob1 = (bf16*)(out + (size_t)(1 * 512 + 256) * 1024);

  prep_kernel<<<dim3(2084), 256, 0, stream>>>(x, w_out, xT, wob0, wob1);
  convqkv_kernel<<<dim3(1024), 256, 0, stream>>>(xT, wob0, wob1, b_out, out,
                                                 w_qkv, b_qkv, qT, kR, vF);
  attn_mfma_kernel<<<dim3(1024), 256, 0, stream>>>(qT, kR, vF, krw, krh, attL);
  attnout_mfma_kernel<<<dim3(8, 4, 8), 256, 0, stream>>>(attL, w_attn, b_attn, out);
}

// Round 6
// 145.018 us; speedup vs baseline: 1.3380x; 1.0190x over previous
//
#include <hip/hip_runtime.h>
#include <hip/hip_bf16.h>

// AttentionConv2d: B=8, C_IN=256, H=W=32 (HW=1024), DK=DV=256, NH=8, DKH=DVH=32,
// C_OUT=512, 3x3 conv pad=1. fp32 storage in/out; bf16 intermediates + MFMA.
//
// Workspace (bf16 elements, EXACTLY 16 MB):
//   xT    [8 b][1024 l][256 ci]  @ 0          read by fused conv3+qkv
//   attL  [8 b][1024 l][256 ch]  @ 0          alias of xT (attn writes after fused done)
//   qT    [64 head][1024][32]    @ 2,097,152
//   kR    [64 head][1024][32]    @ 4,194,304
//   vF    [64 head][16 c][4 q][64 lane][8]  @ 6,291,456   (PV-fragment order)
// prep -> convqkv(fused) -> attn -> attnout.
// R18: attn prologue replaced by MFMA rel-logit tables. Per block:
//   RWfull = krw_bf16 * Q^T (63x64, K=32) and RHfull = krh_bf16 * Q^T, each
//   wave computing one 16-row m-tile (4+4 MFMAs), L2E folded into the bf16
//   conversion of krw/krh. Tables in LDS f32 [64][68]; rw gather + per-chunk
//   rh broadcast reads are bank-conflict-free (verified by bank arithmetic).
//   Deletes stgF staging, 4 prologue barriers, q32[32], ~500 VALU/thread.
// K-loop/epilogue = R17 (zero barriers, direct K/V fragments, rolled loop).

typedef __hip_bfloat16 bf16;
typedef __attribute__((ext_vector_type(8))) short bf16x8;
typedef __attribute__((ext_vector_type(4))) float f32x4;

__device__ __forceinline__ float blo(unsigned int v) { return __uint_as_float(v << 16); }
__device__ __forceinline__ float bhi(unsigned int v) { return __uint_as_float(v & 0xffff0000u); }
__device__ __forceinline__ unsigned short f2bfbits(float f) {
  union { bf16 h; unsigned short u; } cv; cv.h = __float2bfloat16(f); return cv.u;
}
// v_cvt_pk_bf16_f32: dst.lo = bf16(lo), dst.hi = bf16(hi). RNE, 1 VALU op.
__device__ __forceinline__ unsigned int cvt_pk_bf16(float lo, float hi) {
  unsigned int r;
  asm("v_cvt_pk_bf16_f32 %0, %1, %2" : "=v"(r) : "v"(lo), "v"(hi));
  return r;
}
__device__ __forceinline__ float exp2_f(float x) {
#if __has_builtin(__builtin_amdgcn_exp2f)
  return __builtin_amdgcn_exp2f(x);
#else
  return exp2f(x);
#endif
}

// ---------------------------------------------------------------------------
// K0: prep — xT transpose to bf16 + w_out bf16 chunk-blocked into wob0/wob1.
// blocks 0..2047: xT; 2048..2083: w_out. grid 2084.
// ---------------------------------------------------------------------------
__global__ __launch_bounds__(256) void prep_kernel(
    const float* __restrict__ x, const float* __restrict__ wout,
    bf16* __restrict__ xT, bf16* __restrict__ wob0, bf16* __restrict__ wob1)
{
  int bid = blockIdx.x, tid = threadIdx.x;
  if (bid < 2048) {
    __shared__ float t[32 * 33];
    int b = bid >> 8, rem = bid & 255;
    int ci0 = (rem >> 5) * 32, l0 = (rem & 31) * 32;
    {
      int ciL = tid >> 3, lL4 = (tid & 7) * 4;
      float4 v = *(const float4*)(x + (size_t)(b * 256 + ci0 + ciL) * 1024 + l0 + lL4);
      t[ciL * 33 + lL4 + 0] = v.x; t[ciL * 33 + lL4 + 1] = v.y;
      t[ciL * 33 + lL4 + 2] = v.z; t[ciL * 33 + lL4 + 3] = v.w;
    }
    __syncthreads();
    {
      int lL = tid >> 3, cS = (tid & 7) * 4;
      unsigned int p0 = (unsigned int)f2bfbits(t[(cS + 0) * 33 + lL]) |
                        ((unsigned int)f2bfbits(t[(cS + 1) * 33 + lL]) << 16);
      unsigned int p1 = (unsigned int)f2bfbits(t[(cS + 2) * 33 + lL]) |
                        ((unsigned int)f2bfbits(t[(cS + 3) * 33 + lL]) << 16);
      uint2 u2; u2.x = p0; u2.y = p1;
      *(uint2*)(xT + ((size_t)(b * 1024) + l0 + lL) * 256 + ci0 + cS) = u2;
    }
  } else {
    int t0 = (bid - 2048) * 256 + tid;       // 0..9215
#pragma unroll
    for (int s = 0; s < 8; ++s) {
      int u = s * 9216 + t0;                 // dst uint4 index 0..73727
      int chunkblk = u / 2304;
      int within = u - chunkblk * 2304;
      int co63 = within / 36;
      int r = within - co63 * 36;            // kidx*4 + cig
      int kidx = r >> 2, cig = r & 3;
      int co = (chunkblk >> 3) * 64 + co63;
      int ci = (chunkblk & 7) * 32 + cig * 8;
      union { unsigned short h[8]; uint4 u4; } pk;
#pragma unroll
      for (int j = 0; j < 8; ++j)
        pk.h[j] = f2bfbits(wout[(size_t)(co * 256 + ci + j) * 9 + kidx]);
      bf16* dst = (chunkblk < 28) ? (wob0 + (size_t)chunkblk * 18432)
                                  : (wob1 + (size_t)(chunkblk - 28) * 18432);
      *(uint4*)(dst + (size_t)within * 8) = pk.u4;
    }
  }
}

// ---------------------------------------------------------------------------
// K1 (fused): blocks 0..255 = conv3 (3x3, MFMA shift-GEMM, prepacked weights);
// 256..1023 = qkv GEMM. Both only read xT -> co-resident, mutual latency hiding.
// V epilogue writes fragment-ordered vF (R17).
// ---------------------------------------------------------------------------
__global__ __launch_bounds__(256) void convqkv_kernel(
    const bf16* __restrict__ xT,
    const bf16* __restrict__ wob0, const bf16* __restrict__ wob1,
    const float* __restrict__ b_out, float* __restrict__ out,
    const float* __restrict__ wq, const float* __restrict__ b_qkv,
    bf16* __restrict__ qT, bf16* __restrict__ kR, bf16* __restrict__ vW)
{
  __shared__ __align__(16) short smem[27104];
  int tid = threadIdx.x, lane = tid & 63, wave = tid >> 6;
  int m16 = lane & 15, quad = lane >> 4;

  if (blockIdx.x < 256) {
    short* wS = smem;            // [64 co][296]
    short* xS = smem + 18944;    // [6 rows][34 cols][40]
    int bid = blockIdx.x;
    int rc = bid & 7, cotile = (bid >> 3) & 3, b = bid >> 5;
    int y0 = rc * 4;

    f32x4 acc[8];
#pragma unroll
    for (int t = 0; t < 8; ++t) acc[t] = (f32x4){0.f, 0.f, 0.f, 0.f};

    for (int ck = 0; ck < 8; ++ck) {
      __syncthreads();
      int cb = cotile * 8 + ck;
      const bf16* wbase = (cb < 28) ? (wob0 + (size_t)cb * 18432)
                                    : (wob1 + (size_t)(cb - 28) * 18432);
#pragma unroll
      for (int r = 0; r < 9; ++r) {
        int u = r * 256 + tid;
        *(uint4*)(wS + (u / 36) * 296 + (u % 36) * 8) = *(const uint4*)(wbase + (size_t)u * 8);
      }
#pragma unroll
      for (int r = 0; r < 3; ++r) {
        int u = r * 256 + tid;
        int pos = u >> 2, seg = u & 3;
        int row = pos >> 5, col = pos & 31;
        int gy = y0 - 1 + row;
        uint4 val = make_uint4(0u, 0u, 0u, 0u);
        if (gy >= 0 && gy < 32)
          val = *(const uint4*)(xT + ((size_t)(b * 1024) + gy * 32 + col) * 256 + ck * 32 + seg * 8);
        *(uint4*)(xS + (row * 34 + col + 1) * 40 + seg * 8) = val;
      }
      if (tid < 48) {
        int pos = tid >> 2, seg = tid & 3;
        int row = pos >> 1, side = pos & 1;
        *(uint4*)(xS + (row * 34 + side * 33) * 40 + seg * 8) = make_uint4(0u, 0u, 0u, 0u);
      }
      __syncthreads();
#pragma unroll
      for (int kidx = 0; kidx < 9; ++kidx) {
        int dy = kidx / 3, dx = kidx - dy * 3;
        bf16x8 af = *(const bf16x8*)(wS + (wave * 16 + m16) * 296 + kidx * 32 + quad * 8);
#pragma unroll
        for (int t = 0; t < 8; ++t) {
          int row = (t >> 1) + dy;
          int col = (t & 1) * 16 + m16 + dx;
          bf16x8 bf = *(const bf16x8*)(xS + (row * 34 + col) * 40 + quad * 8);
          acc[t] = __builtin_amdgcn_mfma_f32_16x16x32_bf16(af, bf, acc[t], 0, 0, 0);
        }
      }
    }

    int cob = cotile * 64 + wave * 16 + quad * 4;
#pragma unroll
    for (int i = 0; i < 4; ++i) {
      float bv = b_out[cob + i];
#pragma unroll
      for (int t = 0; t < 8; ++t) {
        int y = y0 + (t >> 1), xc = (t & 1) * 16 + m16;
        out[((size_t)(b * 512) + cob + i) * 1024 + y * 32 + xc] = acc[t][i] + bv;
      }
    }
  } else {
    short* aS = smem;            // [64][72]
    short* bS = smem + 4608;     // [128][72]
    int bid2 = blockIdx.x - 256;
    int ltile = bid2 & 7;
    int rest = bid2 >> 3;
    int ctile = rest % 12;
    int b = rest / 12;
    int l0 = ltile * 128;
    int cbase = ctile * 64;

    f32x4 acc[8];
#pragma unroll
    for (int t = 0; t < 8; ++t) acc[t] = (f32x4){0.f, 0.f, 0.f, 0.f};

    for (int ck = 0; ck < 4; ++ck) {
      __syncthreads();
#pragma unroll
      for (int r = 0; r < 4; ++r) {
        int u = r * 256 + tid;
        int c = u >> 4, s4 = u & 15;
        float4 v = *(const float4*)(wq + (size_t)(cbase + c) * 256 + ck * 64 + s4 * 4);
        unsigned int p0 = (unsigned int)f2bfbits(v.x) | ((unsigned int)f2bfbits(v.y) << 16);
        unsigned int p1 = (unsigned int)f2bfbits(v.z) | ((unsigned int)f2bfbits(v.w) << 16);
        uint2 u2; u2.x = p0; u2.y = p1;
        *(uint2*)(aS + c * 72 + s4 * 4) = u2;
      }
#pragma unroll
      for (int r = 0; r < 4; ++r) {
        int u = r * 256 + tid;
        int l = u >> 3, seg = u & 7;
        *(uint4*)(bS + l * 72 + seg * 8) =
            *(const uint4*)(xT + ((size_t)(b * 1024) + l0 + l) * 256 + ck * 64 + seg * 8);
      }
      __syncthreads();
#pragma unroll
      for (int ks = 0; ks < 2; ++ks) {
        bf16x8 af = *(const bf16x8*)(aS + (wave * 16 + m16) * 72 + ks * 32 + quad * 8);
#pragma unroll
        for (int t = 0; t < 8; ++t) {
          bf16x8 bf = *(const bf16x8*)(bS + (t * 16 + m16) * 72 + ks * 32 + quad * 8);
          acc[t] = __builtin_amdgcn_mfma_f32_16x16x32_bf16(af, bf, acc[t], 0, 0, 0);
        }
      }
    }

    __syncthreads();
    short* ldsT = smem + wave * 3072;
    int cb = cbase + wave * 16;
    bool isq = (ctile < 4);
    float bv[4];
#pragma unroll
    for (int i = 0; i < 4; ++i) bv[i] = b_qkv[cb + quad * 4 + i];
#pragma unroll
    for (int t = 0; t < 8; ++t) {
#pragma unroll
      for (int i = 0; i < 4; ++i) {
        float v = acc[t][i] + bv[i];
        if (isq) v *= 0.17677669529663689f;  // 32^-0.5, pre-rel-logits
        ldsT[(t * 16 + m16) * 24 + quad * 4 + i] = (short)f2bfbits(v);
      }
    }
    if (ctile < 8) {
      bf16* dst = isq ? qT : kR;
      int coff = isq ? cb : cb - 256;
#pragma unroll
      for (int rep = 0; rep < 4; ++rep) {
        int u = rep * 64 + lane;
        int l = u >> 1, half = u & 1;
        int c0 = coff + half * 8;
        int head = b * 8 + (c0 >> 5), d0 = c0 & 31;
        *(uint4*)(dst + ((size_t)head * 1024 + l0 + l) * 32 + d0) =
            *(const uint4*)(ldsT + l * 24 + half * 8);
      }
    } else {
      // fragment-ordered vF writes (R17).
      int dcol = lane >> 2, lg = lane & 3;
      int c2 = (cb - 512) + dcol;
      int head = b * 8 + (c2 >> 5), gd = c2 & 31;
      int dt = gd >> 4, m16v = gd & 15;
      int cch = ltile * 2 + (lg >> 1);
      int ksv = lg & 1;
      bf16* vbase = vW + (size_t)head * 32768 + cch * 2048 + (dt * 2 + ksv) * 512 + m16v * 8;
#pragma unroll
      for (int s = 0; s < 4; ++s) {
#pragma unroll
        for (int p = 0; p < 4; ++p) {
          int j0 = lg * 32 + s * 8 + p * 2;
          unsigned int u0 = (unsigned short)ldsT[j0 * 24 + dcol];
          unsigned int u1 = (unsigned short)ldsT[(j0 + 1) * 24 + dcol];
          unsigned int w = u0 | (u1 << 16);
          int quadp = (s & 1) * 2 + (p >> 1);
          int jj = (p & 1) * 2 + (s >> 1) * 4;
          *(unsigned int*)(vbase + quadp * 128 + jj) = w;
        }
      }
    }
  }
}

// ---------------------------------------------------------------------------
// K3: MFMA attention, R18. Grid 1024, 64 q/block. Prologue: rel-logit tables
// via MFMA. RWfull[m][q] = (L2E*krw_bf[m]) . q[row0+q], m in [0,63) (row 63
// zero); RHfull same with krh. Wave w computes m-tile w for both tables:
// A-frag = krw/krh rows w*16+m16 (8 f32 loads * L2E -> cvt_pk, guarded m<63);
// B-frags = qT rows row0+nt*16+m16; 8 MFMAs; scalar writes to LDS [64][68] f32.
// One barrier. Gathers (bank-verified conflict-free):
//   rwreg[par][i] = RWf[(par*16+quad*4+i - (q&31) + 31)][q], q = wave*16+m16
//   rh(c,t') = RHf[(c*2+t' - qy + 31)][q], qy = qt*2 + (q>>5) (uniform row/wave)
// K-loop/epilogue = R17: zero barriers, direct global K (kR) + V (vF, fragment
// order) reads, P in registers via cvt_pk, rolled loop.
// LDS: RWf f32 [64][68] @0 (17408 B); RHf @17408 (17408 B). Total 34816 B.
// ---------------------------------------------------------------------------
__global__ __launch_bounds__(256) void attn_mfma_kernel(
    const bf16* __restrict__ qT, const bf16* __restrict__ kR, const bf16* __restrict__ vW,
    const float* __restrict__ krw, const float* __restrict__ krh,
    bf16* __restrict__ attL)
{
  __shared__ __align__(16) char smem[34816];
  float* RWf = (float*)smem;             // [64 m][68]
  float* RHf = (float*)(smem + 17408);   // [64 m][68]

  const float L2E = 1.4426950408889634f;

  int tid = threadIdx.x;
  int lane = tid & 63, wave = tid >> 6;
  int m16 = lane & 15, quad = lane >> 4;
  int bid = blockIdx.x;
  // same head -> same blockIdx mod 8 -> same XCD (round-robin heuristic)
  int head = ((bid & 7) << 3) | ((bid >> 3) & 7);
  int qt = bid >> 6;                 // 0..15, 64 q rows per block
  int row0 = qt * 64;
  int b = head >> 3, h = head & 7;

  // ---- rel-logit tables via MFMA ----
  {
    int mrow = wave * 16 + m16;          // table row this lane contributes to A
    bool valid = (mrow < 63);
    float4 w0 = make_float4(0.f, 0.f, 0.f, 0.f), w1 = w0, h0 = w0, h1 = w0;
    if (valid) {
      w0 = *(const float4*)(krw + mrow * 32 + quad * 8);
      w1 = *(const float4*)(krw + mrow * 32 + quad * 8 + 4);
      h0 = *(const float4*)(krh + mrow * 32 + quad * 8);
      h1 = *(const float4*)(krh + mrow * 32 + quad * 8 + 4);
    }
    union { unsigned int w[4]; bf16x8 v; } aw, ah;
    aw.w[0] = cvt_pk_bf16(w0.x * L2E, w0.y * L2E);
    aw.w[1] = cvt_pk_bf16(w0.z * L2E, w0.w * L2E);
    aw.w[2] = cvt_pk_bf16(w1.x * L2E, w1.y * L2E);
    aw.w[3] = cvt_pk_bf16(w1.z * L2E, w1.w * L2E);
    ah.w[0] = cvt_pk_bf16(h0.x * L2E, h0.y * L2E);
    ah.w[1] = cvt_pk_bf16(h0.z * L2E, h0.w * L2E);
    ah.w[2] = cvt_pk_bf16(h1.x * L2E, h1.y * L2E);
    ah.w[3] = cvt_pk_bf16(h1.z * L2E, h1.w * L2E);
#pragma unroll
    for (int nt = 0; nt < 4; ++nt) {
      bf16x8 qf = *(const bf16x8*)(
          qT + ((size_t)head * 1024 + row0 + nt * 16 + m16) * 32 + quad * 8);
      f32x4 z = (f32x4){0.f, 0.f, 0.f, 0.f};
      f32x4 dw = __builtin_amdgcn_mfma_f32_16x16x32_bf16(aw.v, qf, z, 0, 0, 0);
      f32x4 dh = __builtin_amdgcn_mfma_f32_16x16x32_bf16(ah.v, qf, z, 0, 0, 0);
#pragma unroll
      for (int i = 0; i < 4; ++i) {
        int mr = wave * 16 + quad * 4 + i;     // D row = m (rel index)
        RWf[mr * 68 + nt * 16 + m16] = dw[i];
        RHf[mr * 68 + nt * 16 + m16] = dh[i];
      }
    }
  }
  __syncthreads();   // tables complete; read-only from here; NO more barriers

  // ---- Q fragment (B-operand) + chunk-invariant RW registers ----
  bf16x8 afrag = *(const bf16x8*)(
      qT + ((size_t)head * 1024 + row0 + wave * 16 + m16) * 32 + quad * 8);
  int qloc = wave * 16 + m16;          // block-local q row
  int qm = qloc & 31;
  float rwreg[2][4];
#pragma unroll
  for (int par = 0; par < 2; ++par)
#pragma unroll
    for (int i = 0; i < 4; ++i)
      rwreg[par][i] = RWf[(par * 16 + quad * 4 + i - qm + 31) * 68 + qloc];
  int qy = qt * 2 + (qloc >> 5);
  const float* rhp = RHf + (31 - qy) * 68 + qloc;   // +c*2*68 (+68) per chunk

  // per-lane global fragment pointers
  const bf16* kp = kR + (size_t)head * 32768 + m16 * 32 + quad * 8;   // +c*2048 +t*512
  const bf16* vp = vW + (size_t)head * 32768 + lane * 8;              // +c*2048 +(dt*2+ks)*512

  f32x4 oacc[2];
  oacc[0] = (f32x4){0.f, 0.f, 0.f, 0.f};
  oacc[1] = (f32x4){0.f, 0.f, 0.f, 0.f};
  float rsp = 0.f;

#pragma unroll 1
  for (int c = 0; c < 16; ++c) {
    // issue all 8 global fragment loads up front (latency overlaps exp below)
    union { uint4 u; bf16x8 v; } kf[4], vf[4];
#pragma unroll
    for (int t = 0; t < 4; ++t)
      kf[t].u = *(const uint4*)(kp + c * 2048 + t * 512);
#pragma unroll
    for (int q = 0; q < 4; ++q)         // q = dt*2 + ks
      vf[q].u = *(const uint4*)(vp + c * 2048 + q * 512);

    // RH for this chunk (uniform row per wave -> broadcast, conflict-free)
    float rh0 = rhp[(c * 2 + 0) * 68];
    float rh1 = rhp[(c * 2 + 1) * 68];

    // QK^T swapped: A = K frag (rows=keys), B = Qfrag (cols=q)
    f32x4 sacc[4];
#pragma unroll
    for (int t = 0; t < 4; ++t) {
      f32x4 z = (f32x4){0.f, 0.f, 0.f, 0.f};
      sacc[t] = __builtin_amdgcn_mfma_f32_16x16x32_bf16(kf[t].v, afrag, z, 0, 0, 0);
    }

    // softmax numerators in-register (lane q = m16, key = t*16+quad*4+i)
    unsigned int pk[4][2];
#pragma unroll
    for (int t = 0; t < 4; ++t) {
      float rh = (t < 2) ? rh0 : rh1;
      float e0 = exp2_f(fmaf(sacc[t][0], L2E, rwreg[t & 1][0] + rh));
      float e1 = exp2_f(fmaf(sacc[t][1], L2E, rwreg[t & 1][1] + rh));
      float e2 = exp2_f(fmaf(sacc[t][2], L2E, rwreg[t & 1][2] + rh));
      float e3 = exp2_f(fmaf(sacc[t][3], L2E, rwreg[t & 1][3] + rh));
      rsp += (e0 + e1) + (e2 + e3);
      pk[t][0] = cvt_pk_bf16(e0, e1);
      pk[t][1] = cvt_pk_bf16(e2, e3);
    }

    // PV: O^T = mfma(Vfrag, P^T). kappa = ks*32 + (j>>2)*16 + quad*4 + (j&3).
#pragma unroll
    for (int ks = 0; ks < 2; ++ks) {
      union { unsigned int w[4]; bf16x8 v; } pf;
      pf.w[0] = pk[2 * ks][0];     pf.w[1] = pk[2 * ks][1];
      pf.w[2] = pk[2 * ks + 1][0]; pf.w[3] = pk[2 * ks + 1][1];
#pragma unroll
      for (int dt = 0; dt < 2; ++dt) {
        oacc[dt] = __builtin_amdgcn_mfma_f32_16x16x32_bf16(vf[dt * 2 + ks].v, pf.v, oacc[dt], 0, 0, 0);
      }
    }
  }

  // ---- epilogue: reduce row-sums across quads, normalize, store ----
  rsp += __shfl_xor(rsp, 16, 64);
  rsp += __shfl_xor(rsp, 32, 64);
  float invs = 1.0f / rsp;
  int grow = row0 + wave * 16 + m16;
#pragma unroll
  for (int dt = 0; dt < 2; ++dt) {
    uint2 st;
    st.x = cvt_pk_bf16(oacc[dt][0] * invs, oacc[dt][1] * invs);
    st.y = cvt_pk_bf16(oacc[dt][2] * invs, oacc[dt][3] * invs);
    *(uint2*)(attL + ((size_t)b * 1024 + grow) * 256 + h * 32 + dt * 16 + quad * 4) = st;
  }
}

// ---------------------------------------------------------------------------
// K4: attnout 1x1 conv as MFMA GEMM 256 x 1024 x 256 per batch. (R6 version)
// Runs last; overwrites the d_out ch256+ regions that hosted wo_bf.
// ---------------------------------------------------------------------------
__global__ __launch_bounds__(256) void attnout_mfma_kernel(
    const bf16* __restrict__ attL, const float* __restrict__ w, const float* __restrict__ bias,
    float* __restrict__ out)
{
  __shared__ __align__(16) short smem[13824];
  short* aS = smem;            // [64 co][72]
  short* bS = smem + 4608;     // [128 l][72]

  int tid = threadIdx.x, lane = tid & 63, wave = tid >> 6;
  int m16 = lane & 15, quad = lane >> 4;
  int l0 = blockIdx.x * 128;
  int cotile = blockIdx.y;
  int b = blockIdx.z;
  int cbase = cotile * 64;

  f32x4 acc[8];
#pragma unroll
  for (int t = 0; t < 8; ++t) acc[t] = (f32x4){0.f, 0.f, 0.f, 0.f};

  for (int ck = 0; ck < 4; ++ck) {
    __syncthreads();
#pragma unroll
    for (int r = 0; r < 4; ++r) {
      int u = r * 256 + tid;
      int c = u >> 4, s4 = u & 15;
      float4 v = *(const float4*)(w + (size_t)(cbase + c) * 256 + ck * 64 + s4 * 4);
      unsigned int p0 = (unsigned int)f2bfbits(v.x) | ((unsigned int)f2bfbits(v.y) << 16);
      unsigned int p1 = (unsigned int)f2bfbits(v.z) | ((unsigned int)f2bfbits(v.w) << 16);
      uint2 u2; u2.x = p0; u2.y = p1;
      *(uint2*)(aS + c * 72 + s4 * 4) = u2;
    }
#pragma unroll
    for (int r = 0; r < 4; ++r) {
      int u = r * 256 + tid;
      int l = u >> 3, seg = u & 7;
      *(uint4*)(bS + l * 72 + seg * 8) =
          *(const uint4*)(attL + ((size_t)(b * 1024) + l0 + l) * 256 + ck * 64 + seg * 8);
    }
    __syncthreads();
#pragma unroll
    for (int ks = 0; ks < 2; ++ks) {
      bf16x8 af = *(const bf16x8*)(aS + (wave * 16 + m16) * 72 + ks * 32 + quad * 8);
#pragma unroll
      for (int t = 0; t < 8; ++t) {
        bf16x8 bf = *(const bf16x8*)(bS + (t * 16 + m16) * 72 + ks * 32 + quad * 8);
        acc[t] = __builtin_amdgcn_mfma_f32_16x16x32_bf16(af, bf, acc[t], 0, 0, 0);
      }
    }
  }

  int co = cbase + wave * 16 + quad * 4;
#pragma unroll
  for (int i = 0; i < 4; ++i) {
    float bv = bias[co + i];
    size_t obase = ((size_t)(b * 512) + 256 + co + i) * 1024 + l0;
#pragma unroll
    for (int t = 0; t < 8; ++t)
      out[obase + t * 16 + m16] = acc[t][i] + bv;
  }
}

// ---------------------------------------------------------------------------
extern "C" void kernel_launch(void* const* d_in, const int* in_sizes, int n_in,
                              void* d_out, int out_size, void* d_ws, size_t ws_size,
                              hipStream_t stream) {
  const float* x      = (const float*)d_in[0];
  const float* w_qkv  = (const float*)d_in[1];
  const float* b_qkv  = (const float*)d_in[2];
  const float* w_attn = (const float*)d_in[3];
  const float* b_attn = (const float*)d_in[4];
  const float* w_out  = (const float*)d_in[5];
  const float* b_out  = (const float*)d_in[6];
  const float* krw    = (const float*)d_in[7];
  const float* krh    = (const float*)d_in[8];
  float* out = (float*)d_out;

  bf16* ws    = (bf16*)d_ws;
  bf16* xT    = ws;                 // [0, 2,097,152)  read by fused conv3+qkv
  bf16* attL  = ws;                 // alias of xT     (attn -> attnout, after fused)
  bf16* qT    = ws + 2097152;       // [2,097,152, 4,194,304)
  bf16* kR    = ws + 4194304;       // [4,194,304, 6,291,456)
  bf16* vF    = ws + 6291456;       // [6,291,456, 8,388,608)  fragment-ordered V

  // wo_bf in d_out's attention half (dead until attnout overwrites it)
  bf16* wob0 = (bf16*)(out + (size_t)(0 * 512 + 256) * 1024);
  bf16* wob1 = (bf16*)(out + (size_t)(1 * 512 + 256) * 1024);

  prep_kernel<<<dim3(2084), 256, 0, stream>>>(x, w_out, xT, wob0, wob1);
  convqkv_kernel<<<dim3(1024), 256, 0, stream>>>(xT, wob0, wob1, b_out, out,
                                                 w_qkv, b_qkv, qT, kR, vF);
  attn_mfma_kernel<<<dim3(1024), 256, 0, stream>>>(qT, kR, vF, krw, krh, attL);
  attnout_mfma_kernel<<<dim3(8, 4, 8), 256, 0, stream>>>(attL, w_attn, b_attn, out);
}

// Round 7
// 138.532 us; speedup vs baseline: 1.4006x; 1.0468x over previous
//
#include <hip/hip_runtime.h>
#include <hip/hip_bf16.h>

// AttentionConv2d: B=8, C_IN=256, H=W=32 (HW=1024), DK=DV=256, NH=8, DKH=DVH=32,
// C_OUT=512, 3x3 conv pad=1. fp32 storage in/out; bf16 intermediates + MFMA.
//
// Workspace (bf16 elements, EXACTLY 16 MB):
//   xT    [8 b][1024 l][256 ci]  @ 0          read by fused conv3+qkv
//   attL  [8 b][1024 l][256 ch]  @ 0          alias of xT (attn writes after fused done)
//   qT    [64 head][1024][32]    @ 2,097,152
//   kR    [64 head][1024][32]    @ 4,194,304
//   vF    [64 head][16 c][4 q][64 lane][8]  @ 6,291,456   (PV-fragment order)
// prep -> convqkv(fused) -> attn -> attnout.
// R19: attn = R18 with 2-wave blocks (128 thr), each wave owning 32 q rows
// (2 Q-subtiles afrag[2] sharing every K/V fragment fetch). Halves the
// per-CU K/V VMEM traffic (the binding pipe: all waves in a block fetch
// identical K/V bytes; 4 waves -> 2 waves = 2 MB -> 1 MB per CU). Grid,
// tables, kappa/vF layout, gathers identical to R18 (qloc-parametric).

typedef __hip_bfloat16 bf16;
typedef __attribute__((ext_vector_type(8))) short bf16x8;
typedef __attribute__((ext_vector_type(4))) float f32x4;

__device__ __forceinline__ float blo(unsigned int v) { return __uint_as_float(v << 16); }
__device__ __forceinline__ float bhi(unsigned int v) { return __uint_as_float(v & 0xffff0000u); }
__device__ __forceinline__ unsigned short f2bfbits(float f) {
  union { bf16 h; unsigned short u; } cv; cv.h = __float2bfloat16(f); return cv.u;
}
// v_cvt_pk_bf16_f32: dst.lo = bf16(lo), dst.hi = bf16(hi). RNE, 1 VALU op.
__device__ __forceinline__ unsigned int cvt_pk_bf16(float lo, float hi) {
  unsigned int r;
  asm("v_cvt_pk_bf16_f32 %0, %1, %2" : "=v"(r) : "v"(lo), "v"(hi));
  return r;
}
__device__ __forceinline__ float exp2_f(float x) {
#if __has_builtin(__builtin_amdgcn_exp2f)
  return __builtin_amdgcn_exp2f(x);
#else
  return exp2f(x);
#endif
}

// ---------------------------------------------------------------------------
// K0: prep — xT transpose to bf16 + w_out bf16 chunk-blocked into wob0/wob1.
// blocks 0..2047: xT; 2048..2083: w_out. grid 2084.
// ---------------------------------------------------------------------------
__global__ __launch_bounds__(256) void prep_kernel(
    const float* __restrict__ x, const float* __restrict__ wout,
    bf16* __restrict__ xT, bf16* __restrict__ wob0, bf16* __restrict__ wob1)
{
  int bid = blockIdx.x, tid = threadIdx.x;
  if (bid < 2048) {
    __shared__ float t[32 * 33];
    int b = bid >> 8, rem = bid & 255;
    int ci0 = (rem >> 5) * 32, l0 = (rem & 31) * 32;
    {
      int ciL = tid >> 3, lL4 = (tid & 7) * 4;
      float4 v = *(const float4*)(x + (size_t)(b * 256 + ci0 + ciL) * 1024 + l0 + lL4);
      t[ciL * 33 + lL4 + 0] = v.x; t[ciL * 33 + lL4 + 1] = v.y;
      t[ciL * 33 + lL4 + 2] = v.z; t[ciL * 33 + lL4 + 3] = v.w;
    }
    __syncthreads();
    {
      int lL = tid >> 3, cS = (tid & 7) * 4;
      unsigned int p0 = (unsigned int)f2bfbits(t[(cS + 0) * 33 + lL]) |
                        ((unsigned int)f2bfbits(t[(cS + 1) * 33 + lL]) << 16);
      unsigned int p1 = (unsigned int)f2bfbits(t[(cS + 2) * 33 + lL]) |
                        ((unsigned int)f2bfbits(t[(cS + 3) * 33 + lL]) << 16);
      uint2 u2; u2.x = p0; u2.y = p1;
      *(uint2*)(xT + ((size_t)(b * 1024) + l0 + lL) * 256 + ci0 + cS) = u2;
    }
  } else {
    int t0 = (bid - 2048) * 256 + tid;       // 0..9215
#pragma unroll
    for (int s = 0; s < 8; ++s) {
      int u = s * 9216 + t0;                 // dst uint4 index 0..73727
      int chunkblk = u / 2304;
      int within = u - chunkblk * 2304;
      int co63 = within / 36;
      int r = within - co63 * 36;            // kidx*4 + cig
      int kidx = r >> 2, cig = r & 3;
      int co = (chunkblk >> 3) * 64 + co63;
      int ci = (chunkblk & 7) * 32 + cig * 8;
      union { unsigned short h[8]; uint4 u4; } pk;
#pragma unroll
      for (int j = 0; j < 8; ++j)
        pk.h[j] = f2bfbits(wout[(size_t)(co * 256 + ci + j) * 9 + kidx]);
      bf16* dst = (chunkblk < 28) ? (wob0 + (size_t)chunkblk * 18432)
                                  : (wob1 + (size_t)(chunkblk - 28) * 18432);
      *(uint4*)(dst + (size_t)within * 8) = pk.u4;
    }
  }
}

// ---------------------------------------------------------------------------
// K1 (fused): blocks 0..255 = conv3 (3x3, MFMA shift-GEMM, prepacked weights);
// 256..1023 = qkv GEMM. Both only read xT -> co-resident, mutual latency hiding.
// V epilogue writes fragment-ordered vF (R17).
// ---------------------------------------------------------------------------
__global__ __launch_bounds__(256) void convqkv_kernel(
    const bf16* __restrict__ xT,
    const bf16* __restrict__ wob0, const bf16* __restrict__ wob1,
    const float* __restrict__ b_out, float* __restrict__ out,
    const float* __restrict__ wq, const float* __restrict__ b_qkv,
    bf16* __restrict__ qT, bf16* __restrict__ kR, bf16* __restrict__ vW)
{
  __shared__ __align__(16) short smem[27104];
  int tid = threadIdx.x, lane = tid & 63, wave = tid >> 6;
  int m16 = lane & 15, quad = lane >> 4;

  if (blockIdx.x < 256) {
    short* wS = smem;            // [64 co][296]
    short* xS = smem + 18944;    // [6 rows][34 cols][40]
    int bid = blockIdx.x;
    int rc = bid & 7, cotile = (bid >> 3) & 3, b = bid >> 5;
    int y0 = rc * 4;

    f32x4 acc[8];
#pragma unroll
    for (int t = 0; t < 8; ++t) acc[t] = (f32x4){0.f, 0.f, 0.f, 0.f};

    for (int ck = 0; ck < 8; ++ck) {
      __syncthreads();
      int cb = cotile * 8 + ck;
      const bf16* wbase = (cb < 28) ? (wob0 + (size_t)cb * 18432)
                                    : (wob1 + (size_t)(cb - 28) * 18432);
#pragma unroll
      for (int r = 0; r < 9; ++r) {
        int u = r * 256 + tid;
        *(uint4*)(wS + (u / 36) * 296 + (u % 36) * 8) = *(const uint4*)(wbase + (size_t)u * 8);
      }
#pragma unroll
      for (int r = 0; r < 3; ++r) {
        int u = r * 256 + tid;
        int pos = u >> 2, seg = u & 3;
        int row = pos >> 5, col = pos & 31;
        int gy = y0 - 1 + row;
        uint4 val = make_uint4(0u, 0u, 0u, 0u);
        if (gy >= 0 && gy < 32)
          val = *(const uint4*)(xT + ((size_t)(b * 1024) + gy * 32 + col) * 256 + ck * 32 + seg * 8);
        *(uint4*)(xS + (row * 34 + col + 1) * 40 + seg * 8) = val;
      }
      if (tid < 48) {
        int pos = tid >> 2, seg = tid & 3;
        int row = pos >> 1, side = pos & 1;
        *(uint4*)(xS + (row * 34 + side * 33) * 40 + seg * 8) = make_uint4(0u, 0u, 0u, 0u);
      }
      __syncthreads();
#pragma unroll
      for (int kidx = 0; kidx < 9; ++kidx) {
        int dy = kidx / 3, dx = kidx - dy * 3;
        bf16x8 af = *(const bf16x8*)(wS + (wave * 16 + m16) * 296 + kidx * 32 + quad * 8);
#pragma unroll
        for (int t = 0; t < 8; ++t) {
          int row = (t >> 1) + dy;
          int col = (t & 1) * 16 + m16 + dx;
          bf16x8 bf = *(const bf16x8*)(xS + (row * 34 + col) * 40 + quad * 8);
          acc[t] = __builtin_amdgcn_mfma_f32_16x16x32_bf16(af, bf, acc[t], 0, 0, 0);
        }
      }
    }

    int cob = cotile * 64 + wave * 16 + quad * 4;
#pragma unroll
    for (int i = 0; i < 4; ++i) {
      float bv = b_out[cob + i];
#pragma unroll
      for (int t = 0; t < 8; ++t) {
        int y = y0 + (t >> 1), xc = (t & 1) * 16 + m16;
        out[((size_t)(b * 512) + cob + i) * 1024 + y * 32 + xc] = acc[t][i] + bv;
      }
    }
  } else {
    short* aS = smem;            // [64][72]
    short* bS = smem + 4608;     // [128][72]
    int bid2 = blockIdx.x - 256;
    int ltile = bid2 & 7;
    int rest = bid2 >> 3;
    int ctile = rest % 12;
    int b = rest / 12;
    int l0 = ltile * 128;
    int cbase = ctile * 64;

    f32x4 acc[8];
#pragma unroll
    for (int t = 0; t < 8; ++t) acc[t] = (f32x4){0.f, 0.f, 0.f, 0.f};

    for (int ck = 0; ck < 4; ++ck) {
      __syncthreads();
#pragma unroll
      for (int r = 0; r < 4; ++r) {
        int u = r * 256 + tid;
        int c = u >> 4, s4 = u & 15;
        float4 v = *(const float4*)(wq + (size_t)(cbase + c) * 256 + ck * 64 + s4 * 4);
        unsigned int p0 = (unsigned int)f2bfbits(v.x) | ((unsigned int)f2bfbits(v.y) << 16);
        unsigned int p1 = (unsigned int)f2bfbits(v.z) | ((unsigned int)f2bfbits(v.w) << 16);
        uint2 u2; u2.x = p0; u2.y = p1;
        *(uint2*)(aS + c * 72 + s4 * 4) = u2;
      }
#pragma unroll
      for (int r = 0; r < 4; ++r) {
        int u = r * 256 + tid;
        int l = u >> 3, seg = u & 7;
        *(uint4*)(bS + l * 72 + seg * 8) =
            *(const uint4*)(xT + ((size_t)(b * 1024) + l0 + l) * 256 + ck * 64 + seg * 8);
      }
      __syncthreads();
#pragma unroll
      for (int ks = 0; ks < 2; ++ks) {
        bf16x8 af = *(const bf16x8*)(aS + (wave * 16 + m16) * 72 + ks * 32 + quad * 8);
#pragma unroll
        for (int t = 0; t < 8; ++t) {
          bf16x8 bf = *(const bf16x8*)(bS + (t * 16 + m16) * 72 + ks * 32 + quad * 8);
          acc[t] = __builtin_amdgcn_mfma_f32_16x16x32_bf16(af, bf, acc[t], 0, 0, 0);
        }
      }
    }

    __syncthreads();
    short* ldsT = smem + wave * 3072;
    int cb = cbase + wave * 16;
    bool isq = (ctile < 4);
    float bv[4];
#pragma unroll
    for (int i = 0; i < 4; ++i) bv[i] = b_qkv[cb + quad * 4 + i];
#pragma unroll
    for (int t = 0; t < 8; ++t) {
#pragma unroll
      for (int i = 0; i < 4; ++i) {
        float v = acc[t][i] + bv[i];
        if (isq) v *= 0.17677669529663689f;  // 32^-0.5, pre-rel-logits
        ldsT[(t * 16 + m16) * 24 + quad * 4 + i] = (short)f2bfbits(v);
      }
    }
    if (ctile < 8) {
      bf16* dst = isq ? qT : kR;
      int coff = isq ? cb : cb - 256;
#pragma unroll
      for (int rep = 0; rep < 4; ++rep) {
        int u = rep * 64 + lane;
        int l = u >> 1, half = u & 1;
        int c0 = coff + half * 8;
        int head = b * 8 + (c0 >> 5), d0 = c0 & 31;
        *(uint4*)(dst + ((size_t)head * 1024 + l0 + l) * 32 + d0) =
            *(const uint4*)(ldsT + l * 24 + half * 8);
      }
    } else {
      // fragment-ordered vF writes (R17).
      int dcol = lane >> 2, lg = lane & 3;
      int c2 = (cb - 512) + dcol;
      int head = b * 8 + (c2 >> 5), gd = c2 & 31;
      int dt = gd >> 4, m16v = gd & 15;
      int cch = ltile * 2 + (lg >> 1);
      int ksv = lg & 1;
      bf16* vbase = vW + (size_t)head * 32768 + cch * 2048 + (dt * 2 + ksv) * 512 + m16v * 8;
#pragma unroll
      for (int s = 0; s < 4; ++s) {
#pragma unroll
        for (int p = 0; p < 4; ++p) {
          int j0 = lg * 32 + s * 8 + p * 2;
          unsigned int u0 = (unsigned short)ldsT[j0 * 24 + dcol];
          unsigned int u1 = (unsigned short)ldsT[(j0 + 1) * 24 + dcol];
          unsigned int w = u0 | (u1 << 16);
          int quadp = (s & 1) * 2 + (p >> 1);
          int jj = (p & 1) * 2 + (s >> 1) * 4;
          *(unsigned int*)(vbase + quadp * 128 + jj) = w;
        }
      }
    }
  }
}

// ---------------------------------------------------------------------------
// K3: MFMA attention, R19. Grid 1024 x 128 threads (2 waves). Each wave owns
// 32 q rows = 2 subtiles (afrag[2]) sharing every K/V fragment fetch (halves
// the binding per-CU VMEM traffic vs R18's 4-wave blocks). Prologue: rel-logit
// tables via MFMA; wave w builds m-tiles {2w, 2w+1} of RWf/RHf (16 MFMAs/wave).
// One barrier. Gathers (qloc-parametric, identical formulas to R18):
//   rwreg[sub][par][i] = RWf[(par*16+quad*4+i - (qloc&31) + 31)][qloc]
//   rh(sub; c,t') = RHf[(c*2+t' - qy + 31)][qloc], qy = qt*2 + wave
// K-loop: zero barriers, direct global K (kR) + V (vF fragment-order) reads,
// P in registers via cvt_pk (kappa PV B-frag), rolled loop.
// LDS: RWf f32 [64][68] @0 (17408 B); RHf @17408. Total 34816 B.
// ---------------------------------------------------------------------------
__global__ __launch_bounds__(128) void attn_mfma_kernel(
    const bf16* __restrict__ qT, const bf16* __restrict__ kR, const bf16* __restrict__ vW,
    const float* __restrict__ krw, const float* __restrict__ krh,
    bf16* __restrict__ attL)
{
  __shared__ __align__(16) char smem[34816];
  float* RWf = (float*)smem;             // [64 m][68]
  float* RHf = (float*)(smem + 17408);   // [64 m][68]

  const float L2E = 1.4426950408889634f;

  int tid = threadIdx.x;
  int lane = tid & 63, wave = tid >> 6;      // wave in {0,1}
  int m16 = lane & 15, quad = lane >> 4;
  int bid = blockIdx.x;
  // same head -> same blockIdx mod 8 -> same XCD (round-robin heuristic)
  int head = ((bid & 7) << 3) | ((bid >> 3) & 7);
  int qt = bid >> 6;                 // 0..15, 64 q rows per block
  int row0 = qt * 64;
  int b = head >> 3, h = head & 7;

  // ---- rel-logit tables via MFMA (wave w: m-tiles 2w, 2w+1) ----
#pragma unroll
  for (int mt = 0; mt < 2; ++mt) {
    int mtile = wave * 2 + mt;
    int mrow = mtile * 16 + m16;
    bool valid = (mrow < 63);
    float4 w0 = make_float4(0.f, 0.f, 0.f, 0.f), w1 = w0, h0 = w0, h1 = w0;
    if (valid) {
      w0 = *(const float4*)(krw + mrow * 32 + quad * 8);
      w1 = *(const float4*)(krw + mrow * 32 + quad * 8 + 4);
      h0 = *(const float4*)(krh + mrow * 32 + quad * 8);
      h1 = *(const float4*)(krh + mrow * 32 + quad * 8 + 4);
    }
    union { unsigned int w[4]; bf16x8 v; } aw, ah;
    aw.w[0] = cvt_pk_bf16(w0.x * L2E, w0.y * L2E);
    aw.w[1] = cvt_pk_bf16(w0.z * L2E, w0.w * L2E);
    aw.w[2] = cvt_pk_bf16(w1.x * L2E, w1.y * L2E);
    aw.w[3] = cvt_pk_bf16(w1.z * L2E, w1.w * L2E);
    ah.w[0] = cvt_pk_bf16(h0.x * L2E, h0.y * L2E);
    ah.w[1] = cvt_pk_bf16(h0.z * L2E, h0.w * L2E);
    ah.w[2] = cvt_pk_bf16(h1.x * L2E, h1.y * L2E);
    ah.w[3] = cvt_pk_bf16(h1.z * L2E, h1.w * L2E);
#pragma unroll
    for (int nt = 0; nt < 4; ++nt) {
      bf16x8 qf = *(const bf16x8*)(
          qT + ((size_t)head * 1024 + row0 + nt * 16 + m16) * 32 + quad * 8);
      f32x4 z = (f32x4){0.f, 0.f, 0.f, 0.f};
      f32x4 dw = __builtin_amdgcn_mfma_f32_16x16x32_bf16(aw.v, qf, z, 0, 0, 0);
      f32x4 dh = __builtin_amdgcn_mfma_f32_16x16x32_bf16(ah.v, qf, z, 0, 0, 0);
#pragma unroll
      for (int i = 0; i < 4; ++i) {
        int mr = mtile * 16 + quad * 4 + i;     // D row = m (rel index)
        RWf[mr * 68 + nt * 16 + m16] = dw[i];
        RHf[mr * 68 + nt * 16 + m16] = dh[i];
      }
    }
  }
  __syncthreads();   // tables complete; read-only from here; NO more barriers

  // ---- Q fragments (B-operand) + chunk-invariant RW registers, per subtile
  bf16x8 afrag[2];
  float rwreg[2][2][4];
  int qloc0 = wave * 32 + m16;       // sub 0; sub 1 adds 16
#pragma unroll
  for (int sub = 0; sub < 2; ++sub) {
    int qloc = qloc0 + sub * 16;
    afrag[sub] = *(const bf16x8*)(
        qT + ((size_t)head * 1024 + row0 + qloc) * 32 + quad * 8);
    int qm = qloc & 31;
#pragma unroll
    for (int par = 0; par < 2; ++par)
#pragma unroll
      for (int i = 0; i < 4; ++i)
        rwreg[sub][par][i] = RWf[(par * 16 + quad * 4 + i - qm + 31) * 68 + qloc];
  }
  int qy = qt * 2 + wave;            // (qloc>>5) == wave for both subtiles
  const float* rhp0 = RHf + (31 - qy) * 68 + qloc0;        // +c*2*68 per chunk
  const float* rhp1 = rhp0 + 16;                           // sub 1 column

  // per-lane global fragment pointers (wave-independent: subs share fetches)
  const bf16* kp = kR + (size_t)head * 32768 + m16 * 32 + quad * 8;   // +c*2048 +t*512
  const bf16* vp = vW + (size_t)head * 32768 + lane * 8;              // +c*2048 +(dt*2+ks)*512

  f32x4 oacc[2][2];
#pragma unroll
  for (int sub = 0; sub < 2; ++sub) {
    oacc[sub][0] = (f32x4){0.f, 0.f, 0.f, 0.f};
    oacc[sub][1] = (f32x4){0.f, 0.f, 0.f, 0.f};
  }
  float rsp[2] = {0.f, 0.f};

#pragma unroll 1
  for (int c = 0; c < 16; ++c) {
    // issue all 8 shared fragment loads up front (latency overlaps exp below)
    union { uint4 u; bf16x8 v; } kf[4], vf[4];
#pragma unroll
    for (int t = 0; t < 4; ++t)
      kf[t].u = *(const uint4*)(kp + c * 2048 + t * 512);
#pragma unroll
    for (int q = 0; q < 4; ++q)         // q = dt*2 + ks
      vf[q].u = *(const uint4*)(vp + c * 2048 + q * 512);

    // RH for this chunk (per sub column; rows uniform per wave)
    float rh[2][2];
    rh[0][0] = rhp0[(c * 2 + 0) * 68];  rh[0][1] = rhp0[(c * 2 + 1) * 68];
    rh[1][0] = rhp1[(c * 2 + 0) * 68];  rh[1][1] = rhp1[(c * 2 + 1) * 68];

    // QK^T swapped: A = K frag (rows=keys), B = Qfrag[sub] (cols=q)
    f32x4 sacc[2][4];
#pragma unroll
    for (int t = 0; t < 4; ++t) {
      f32x4 z = (f32x4){0.f, 0.f, 0.f, 0.f};
#pragma unroll
      for (int sub = 0; sub < 2; ++sub)
        sacc[sub][t] = __builtin_amdgcn_mfma_f32_16x16x32_bf16(kf[t].v, afrag[sub], z, 0, 0, 0);
    }

    // softmax numerators in-register (lane q = qloc, key = t*16+quad*4+i)
    unsigned int pk[2][4][2];
#pragma unroll
    for (int sub = 0; sub < 2; ++sub) {
#pragma unroll
      for (int t = 0; t < 4; ++t) {
        float rhv = rh[sub][t >> 1];
        float e0 = exp2_f(fmaf(sacc[sub][t][0], L2E, rwreg[sub][t & 1][0] + rhv));
        float e1 = exp2_f(fmaf(sacc[sub][t][1], L2E, rwreg[sub][t & 1][1] + rhv));
        float e2 = exp2_f(fmaf(sacc[sub][t][2], L2E, rwreg[sub][t & 1][2] + rhv));
        float e3 = exp2_f(fmaf(sacc[sub][t][3], L2E, rwreg[sub][t & 1][3] + rhv));
        rsp[sub] += (e0 + e1) + (e2 + e3);
        pk[sub][t][0] = cvt_pk_bf16(e0, e1);
        pk[sub][t][1] = cvt_pk_bf16(e2, e3);
      }
    }

    // PV: O^T = mfma(Vfrag, P^T). kappa = ks*32 + (j>>2)*16 + quad*4 + (j&3).
#pragma unroll
    for (int ks = 0; ks < 2; ++ks) {
#pragma unroll
      for (int sub = 0; sub < 2; ++sub) {
        union { unsigned int w[4]; bf16x8 v; } pf;
        pf.w[0] = pk[sub][2 * ks][0];     pf.w[1] = pk[sub][2 * ks][1];
        pf.w[2] = pk[sub][2 * ks + 1][0]; pf.w[3] = pk[sub][2 * ks + 1][1];
#pragma unroll
        for (int dt = 0; dt < 2; ++dt) {
          oacc[sub][dt] = __builtin_amdgcn_mfma_f32_16x16x32_bf16(
              vf[dt * 2 + ks].v, pf.v, oacc[sub][dt], 0, 0, 0);
        }
      }
    }
  }

  // ---- epilogue: reduce row-sums across quads, normalize, store ----
#pragma unroll
  for (int sub = 0; sub < 2; ++sub) {
    rsp[sub] += __shfl_xor(rsp[sub], 16, 64);
    rsp[sub] += __shfl_xor(rsp[sub], 32, 64);
    float invs = 1.0f / rsp[sub];
    int grow = row0 + qloc0 + sub * 16;
#pragma unroll
    for (int dt = 0; dt < 2; ++dt) {
      uint2 st;
      st.x = cvt_pk_bf16(oacc[sub][dt][0] * invs, oacc[sub][dt][1] * invs);
      st.y = cvt_pk_bf16(oacc[sub][dt][2] * invs, oacc[sub][dt][3] * invs);
      *(uint2*)(attL + ((size_t)b * 1024 + grow) * 256 + h * 32 + dt * 16 + quad * 4) = st;
    }
  }
}

// ---------------------------------------------------------------------------
// K4: attnout 1x1 conv as MFMA GEMM 256 x 1024 x 256 per batch. (R6 version)
// Runs last; overwrites the d_out ch256+ regions that hosted wo_bf.
// ---------------------------------------------------------------------------
__global__ __launch_bounds__(256) void attnout_mfma_kernel(
    const bf16* __restrict__ attL, const float* __restrict__ w, const float* __restrict__ bias,
    float* __restrict__ out)
{
  __shared__ __align__(16) short smem[13824];
  short* aS = smem;            // [64 co][72]
  short* bS = smem + 4608;     // [128 l][72]

  int tid = threadIdx.x, lane = tid & 63, wave = tid >> 6;
  int m16 = lane & 15, quad = lane >> 4;
  int l0 = blockIdx.x * 128;
  int cotile = blockIdx.y;
  int b = blockIdx.z;
  int cbase = cotile * 64;

  f32x4 acc[8];
#pragma unroll
  for (int t = 0; t < 8; ++t) acc[t] = (f32x4){0.f, 0.f, 0.f, 0.f};

  for (int ck = 0; ck < 4; ++ck) {
    __syncthreads();
#pragma unroll
    for (int r = 0; r < 4; ++r) {
      int u = r * 256 + tid;
      int c = u >> 4, s4 = u & 15;
      float4 v = *(const float4*)(w + (size_t)(cbase + c) * 256 + ck * 64 + s4 * 4);
      unsigned int p0 = (unsigned int)f2bfbits(v.x) | ((unsigned int)f2bfbits(v.y) << 16);
      unsigned int p1 = (unsigned int)f2bfbits(v.z) | ((unsigned int)f2bfbits(v.w) << 16);
      uint2 u2; u2.x = p0; u2.y = p1;
      *(uint2*)(aS + c * 72 + s4 * 4) = u2;
    }
#pragma unroll
    for (int r = 0; r < 4; ++r) {
      int u = r * 256 + tid;
      int l = u >> 3, seg = u & 7;
      *(uint4*)(bS + l * 72 + seg * 8) =
          *(const uint4*)(attL + ((size_t)(b * 1024) + l0 + l) * 256 + ck * 64 + seg * 8);
    }
    __syncthreads();
#pragma unroll
    for (int ks = 0; ks < 2; ++ks) {
      bf16x8 af = *(const bf16x8*)(aS + (wave * 16 + m16) * 72 + ks * 32 + quad * 8);
#pragma unroll
      for (int t = 0; t < 8; ++t) {
        bf16x8 bf = *(const bf16x8*)(bS + (t * 16 + m16) * 72 + ks * 32 + quad * 8);
        acc[t] = __builtin_amdgcn_mfma_f32_16x16x32_bf16(af, bf, acc[t], 0, 0, 0);
      }
    }
  }

  int co = cbase + wave * 16 + quad * 4;
#pragma unroll
  for (int i = 0; i < 4; ++i) {
    float bv = bias[co + i];
    size_t obase = ((size_t)(b * 512) + 256 + co + i) * 1024 + l0;
#pragma unroll
    for (int t = 0; t < 8; ++t)
      out[obase + t * 16 + m16] = acc[t][i] + bv;
  }
}

// ---------------------------------------------------------------------------
extern "C" void kernel_launch(void* const* d_in, const int* in_sizes, int n_in,
                              void* d_out, int out_size, void* d_ws, size_t ws_size,
                              hipStream_t stream) {
  const float* x      = (const float*)d_in[0];
  const float* w_qkv  = (const float*)d_in[1];
  const float* b_qkv  = (const float*)d_in[2];
  const float* w_attn = (const float*)d_in[3];
  const float* b_attn = (const float*)d_in[4];
  const float* w_out  = (const float*)d_in[5];
  const float* b_out  = (const float*)d_in[6];
  const float* krw    = (const float*)d_in[7];
  const float* krh    = (const float*)d_in[8];
  float* out = (float*)d_out;

  bf16* ws    = (bf16*)d_ws;
  bf16* xT    = ws;                 // [0, 2,097,152)  read by fused conv3+qkv
  bf16* attL  = ws;                 // alias of xT     (attn -> attnout, after fused)
  bf16* qT    = ws + 2097152;       // [2,097,152, 4,194,304)
  bf16* kR    = ws + 4194304;       // [4,194,304, 6,291,456)
  bf16* vF    = ws + 6291456;       // [6,291,456, 8,388,608)  fragment-ordered V

  // wo_bf in d_out's attention half (dead until attnout overwrites it)
  bf16* wob0 = (bf16*)(out + (size_t)(0 * 512 + 256) * 1024);
  bf16* wob1 = (bf16*)(out + (size_t)(1 * 512 + 256) * 1024);

  prep_kernel<<<dim3(2084), 256, 0, stream>>>(x, w_out, xT, wob0, wob1);
  convqkv_kernel<<<dim3(1024), 256, 0, stream>>>(xT, wob0, wob1, b_out, out,
                                                 w_qkv, b_qkv, qT, kR, vF);
  attn_mfma_kernel<<<dim3(1024), 128, 0, stream>>>(qT, kR, vF, krw, krh, attL);
  attnout_mfma_kernel<<<dim3(8, 4, 8), 256, 0, stream>>>(attL, w_attn, b_attn, out);
}